// Round 1
// baseline (5809.502 us; speedup 1.0000x reference)
//
#include <hip/hip_runtime.h>

static inline int cdiv_ll(long long a, long long b){ return (int)((a + b - 1) / b); }

// ---------------- GEMM: Y[M,64] = op(X[M,K]) @ W[K,64] (+bias) (+relu) ----------------
template<int K, bool RELU_IN, bool RELU_OUT, bool BIAS>
__global__ __launch_bounds__(256) void gemm_n64(
    const float* __restrict__ X, const float* __restrict__ W,
    const float* __restrict__ bias, float* __restrict__ Y, int M)
{
  __shared__ float Wl[K * 64];
  __shared__ float Xl[4][K];
  for (int i = threadIdx.x; i < K * 16; i += 256)
    reinterpret_cast<float4*>(Wl)[i] = reinterpret_cast<const float4*>(W)[i];
  const int c = threadIdx.x & 63;
  const int r = threadIdx.x >> 6;
  const float bv = BIAS ? bias[c] : 0.0f;

  for (long long rb = (long long)blockIdx.x * 4; rb < M; rb += (long long)gridDim.x * 4) {
    __syncthreads();  // protect Xl (prev iter readers) + ensure Wl visible on iter 0
    for (int i = threadIdx.x; i < K; i += 256) {  // K float4 loads = 4 rows * K/4
      int rr = i / (K / 4), kk = i % (K / 4);
      if (rb + rr < M) {
        float4 v = reinterpret_cast<const float4*>(X + (rb + rr) * K)[kk];
        if (RELU_IN) {
          v.x = fmaxf(v.x, 0.f); v.y = fmaxf(v.y, 0.f);
          v.z = fmaxf(v.z, 0.f); v.w = fmaxf(v.w, 0.f);
        }
        reinterpret_cast<float4*>(&Xl[rr][0])[kk] = v;
      }
    }
    __syncthreads();
    if (rb + r < M) {
      float acc = 0.f;
      #pragma unroll
      for (int k = 0; k < K; ++k) acc = fmaf(Xl[r][k], Wl[k * 64 + c], acc);
      float o = acc + bv;
      if (RELU_OUT) o = fmaxf(o, 0.f);
      Y[(rb + r) * 64 + c] = o;
    }
  }
}

// ---------------- A = P + b1 (broadcast bias over 64 cols) ----------------
__global__ __launch_bounds__(256) void init_bias(
    const float* __restrict__ P, const float* __restrict__ b,
    float* __restrict__ A, long long n)  // n = total floats (N*64)
{
  long long i = (long long)blockIdx.x * 256 + threadIdx.x;  // float4 index
  if (i * 4 >= n) return;
  float4 v = reinterpret_cast<const float4*>(P)[i];
  int c = (int)((i * 4) & 63);
  v.x += b[c]; v.y += b[c + 1]; v.z += b[c + 2]; v.w += b[c + 3];
  reinterpret_cast<float4*>(A)[i] = v;
}

// ---------------- A[dst] += P[src] over edges (atomic scatter-add) ----------------
__global__ __launch_bounds__(256) void edge_agg(
    const int* __restrict__ src, const int* __restrict__ dst,
    const float* __restrict__ P, float* __restrict__ A, int E)
{
  long long t = (long long)blockIdx.x * 256 + threadIdx.x;
  long long e = t >> 4;
  int q = (int)(t & 15);
  if (e >= E) return;
  int s = src[e], d = dst[e];
  float4 v = reinterpret_cast<const float4*>(P + (long long)s * 64)[q];
  float* ap = A + (long long)d * 64 + q * 4;
  atomicAdd(ap + 0, v.x);
  atomicAdd(ap + 1, v.y);
  atomicAdd(ap + 2, v.z);
  atomicAdd(ap + 3, v.w);
}

// ---------------- BN stats: sum / sumsq of relu(A) per column ----------------
__global__ __launch_bounds__(256) void bn_stats(
    const float* __restrict__ A, float* __restrict__ stats, int M)
{
  const int c = threadIdx.x & 63;
  const int r = threadIdx.x >> 6;
  float s = 0.f, s2 = 0.f;
  for (long long row = (long long)blockIdx.x * 4 + r; row < M; row += (long long)gridDim.x * 4) {
    float v = fmaxf(A[row * 64 + c], 0.f);
    s += v; s2 += v * v;
  }
  __shared__ float red[2][4][64];
  red[0][r][c] = s; red[1][r][c] = s2;
  __syncthreads();
  if (r == 0) {
    s  = red[0][0][c] + red[0][1][c] + red[0][2][c] + red[0][3][c];
    s2 = red[1][0][c] + red[1][1][c] + red[1][2][c] + red[1][3][c];
    atomicAdd(&stats[c], s);
    atomicAdd(&stats[64 + c], s2);
  }
}

// ---------------- fold BN into W2/b2: W2f[k][j]=s_k*W2[k][j]; b2f=b2+sum_k(be_k-mu_k*s_k)W2[k][j]
__global__ void bn_fold(
    const float* __restrict__ stats, const float* __restrict__ g, const float* __restrict__ be,
    const float* __restrict__ W2, const float* __restrict__ b2,
    float* __restrict__ W2f, float* __restrict__ b2f, float invN)
{
  int j = threadIdx.x;  // 0..63
  __shared__ float sc[64], sh[64];
  float mu = stats[j] * invN;
  float var = stats[64 + j] * invN - mu * mu;
  float s = g[j] * rsqrtf(var + 1e-5f);
  sc[j] = s;
  sh[j] = be[j] - mu * s;
  __syncthreads();
  float acc = b2[j];
  for (int k = 0; k < 64; ++k) {
    float w = W2[k * 64 + j];
    W2f[k * 64 + j] = sc[k] * w;
    acc += sh[k] * w;
  }
  b2f[j] = acc;
}

// ---------------- global add pool: out[batch[row]] += H[row] ----------------
__global__ __launch_bounds__(256) void pool_kernel(
    const float* __restrict__ H, const int* __restrict__ batch,
    float* __restrict__ out, int M)
{
  long long t = (long long)blockIdx.x * 256 + threadIdx.x;
  long long row = t >> 4;
  int q = (int)(t & 15);
  if (row >= M) return;
  int gr = batch[row];
  float4 v = reinterpret_cast<const float4*>(H + row * 64)[q];
  float* op = out + (long long)gr * 64 + q * 4;
  atomicAdd(op + 0, v.x);
  atomicAdd(op + 1, v.y);
  atomicAdd(op + 2, v.z);
  atomicAdd(op + 3, v.w);
}

extern "C" void kernel_launch(void* const* d_in, const int* in_sizes, int n_in,
                              void* d_out, int out_size, void* d_ws, size_t ws_size,
                              hipStream_t stream) {
  const float* x      = (const float*)d_in[0];
  const int*   ei     = (const int*)d_in[1];
  const int*   batch  = (const int*)d_in[2];
  const float* W1_0 = (const float*)d_in[3];
  const float* b1_0 = (const float*)d_in[4];
  const float* g_0  = (const float*)d_in[5];
  const float* be_0 = (const float*)d_in[6];
  const float* W2_0 = (const float*)d_in[7];
  const float* b2_0 = (const float*)d_in[8];
  const float* W1_1 = (const float*)d_in[9];
  const float* b1_1 = (const float*)d_in[10];
  const float* g_1  = (const float*)d_in[11];
  const float* be_1 = (const float*)d_in[12];
  const float* W2_1 = (const float*)d_in[13];
  const float* b2_1 = (const float*)d_in[14];

  const int N = in_sizes[0] / 128;
  const int E = in_sizes[1] / 2;
  const int G = (out_size - N * 64) / 64;
  const int* srcI = ei;
  const int* dstI = ei + E;

  float* outG = (float*)d_out;                       // [G,64]
  float* outH = (float*)d_out + (long long)G * 64;   // [N,64]

  float* ws0    = (float*)d_ws;                      // [N,64] scratch
  float* stats0 = ws0 + (long long)N * 64;
  float* stats1 = stats0 + 128;
  float* W2f0   = stats1 + 128;
  float* b2f0   = W2f0 + 64 * 64;
  float* W2f1   = b2f0 + 64;
  float* b2f1   = W2f1 + 64 * 64;

  hipMemsetAsync(stats0, 0, 256 * sizeof(float), stream);
  hipMemsetAsync(d_out, 0, (long long)G * 64 * sizeof(float), stream);

  const long long n64 = (long long)N * 64;
  const int gemmGrid = 2048;
  const int ebGrid   = cdiv_ll((long long)E * 16, 256);
  const int ibGrid   = cdiv_ll(n64 / 4, 256);

  // ---- layer 0 ----
  // p0 = x @ W1_0                     (ws0)
  gemm_n64<128, false, false, false><<<gemmGrid, 256, 0, stream>>>(x, W1_0, nullptr, ws0, N);
  // a0 = p0 + b1_0                    (outH)
  init_bias<<<ibGrid, 256, 0, stream>>>(ws0, b1_0, outH, n64);
  // a0[dst] += p0[src]
  edge_agg<<<ebGrid, 256, 0, stream>>>(srcI, dstI, ws0, outH, E);
  // BN stats of relu(a0); fold into W2_0/b2_0
  bn_stats<<<256, 256, 0, stream>>>(outH, stats0, N);
  bn_fold<<<1, 64, 0, stream>>>(stats0, g_0, be_0, W2_0, b2_0, W2f0, b2f0, 1.0f / N);
  // h1 = relu(relu(a0) @ W2f0 + b2f0) (ws0)
  gemm_n64<64, true, true, true><<<gemmGrid, 256, 0, stream>>>(outH, W2f0, b2f0, ws0, N);

  // ---- layer 1 ----
  // p1 = h1 @ W1_1                    (outH)
  gemm_n64<64, false, false, false><<<gemmGrid, 256, 0, stream>>>(ws0, W1_1, nullptr, outH, N);
  // a1 = p1 + b1_1                    (ws0)
  init_bias<<<ibGrid, 256, 0, stream>>>(outH, b1_1, ws0, n64);
  // a1[dst] += p1[src]
  edge_agg<<<ebGrid, 256, 0, stream>>>(srcI, dstI, outH, ws0, E);
  bn_stats<<<256, 256, 0, stream>>>(ws0, stats1, N);
  bn_fold<<<1, 64, 0, stream>>>(stats1, g_1, be_1, W2_1, b2_1, W2f1, b2f1, 1.0f / N);
  // h2 = relu(relu(a1) @ W2f1 + b2f1) (outH -- final node features)
  gemm_n64<64, true, true, true><<<gemmGrid, 256, 0, stream>>>(ws0, W2f1, b2f1, outH, N);

  // ---- global add pool ----
  pool_kernel<<<cdiv_ll((long long)N * 16, 256), 256, 0, stream>>>(outH, batch, outG, N);
}

// Round 2
// 964.413 us; speedup vs baseline: 6.0239x; 6.0239x over previous
//
#include <hip/hip_runtime.h>

static inline int cdiv_ll(long long a, long long b){ return (int)((a + b - 1) / b); }

#define SCAN_BS 1024  // elements per scan block (256 threads x 4)

// ---------------- GEMM: Y[M,64] = op(X[M,K]) @ W[K,64] (+bias) (+relu) ----------------
template<int K, bool RELU_IN, bool RELU_OUT, bool BIAS>
__global__ __launch_bounds__(256) void gemm_n64(
    const float* __restrict__ X, const float* __restrict__ W,
    const float* __restrict__ bias, float* __restrict__ Y, int M)
{
  __shared__ float Wl[K * 64];
  __shared__ float Xl[4][K];
  for (int i = threadIdx.x; i < K * 16; i += 256)
    reinterpret_cast<float4*>(Wl)[i] = reinterpret_cast<const float4*>(W)[i];
  const int c = threadIdx.x & 63;
  const int r = threadIdx.x >> 6;
  const float bv = BIAS ? bias[c] : 0.0f;

  for (long long rb = (long long)blockIdx.x * 4; rb < M; rb += (long long)gridDim.x * 4) {
    __syncthreads();  // protect Xl (prev iter readers) + ensure Wl visible on iter 0
    for (int i = threadIdx.x; i < K; i += 256) {
      int rr = i / (K / 4), kk = i % (K / 4);
      if (rb + rr < M) {
        float4 v = reinterpret_cast<const float4*>(X + (rb + rr) * K)[kk];
        if (RELU_IN) {
          v.x = fmaxf(v.x, 0.f); v.y = fmaxf(v.y, 0.f);
          v.z = fmaxf(v.z, 0.f); v.w = fmaxf(v.w, 0.f);
        }
        reinterpret_cast<float4*>(&Xl[rr][0])[kk] = v;
      }
    }
    __syncthreads();
    if (rb + r < M) {
      float acc = 0.f;
      #pragma unroll
      for (int k = 0; k < K; ++k) acc = fmaf(Xl[r][k], Wl[k * 64 + c], acc);
      float o = acc + bv;
      if (RELU_OUT) o = fmaxf(o, 0.f);
      Y[(rb + r) * 64 + c] = o;
    }
  }
}

// ---------------- CSR build: histogram of dst ----------------
__global__ __launch_bounds__(256) void hist_dst(
    const int* __restrict__ dst, int* __restrict__ cnt, int E)
{
  int e = blockIdx.x * 256 + threadIdx.x;
  if (e < E) atomicAdd(&cnt[dst[e]], 1);
}

// ---------------- scan step 1: per-block partial sums ----------------
__global__ __launch_bounds__(256) void scan_partial_sums(
    const int* __restrict__ cnt, int* __restrict__ partials, int n)
{
  __shared__ int red[256];
  int base = blockIdx.x * SCAN_BS;
  int s = 0;
  for (int i = threadIdx.x; i < SCAN_BS; i += 256) {
    int g = base + i;
    if (g < n) s += cnt[g];
  }
  red[threadIdx.x] = s;
  __syncthreads();
  for (int off = 128; off > 0; off >>= 1) {
    if (threadIdx.x < off) red[threadIdx.x] += red[threadIdx.x + off];
    __syncthreads();
  }
  if (threadIdx.x == 0) partials[blockIdx.x] = red[0];
}

// ---------------- scan step 2: exclusive scan of partials (tiny) ----------------
__global__ void scan_scan_partials(int* __restrict__ partials, int nb)
{
  if (threadIdx.x == 0 && blockIdx.x == 0) {
    int acc = 0;
    for (int i = 0; i < nb; ++i) { int v = partials[i]; partials[i] = acc; acc += v; }
  }
}

// ---------------- scan step 3: per-block exclusive scan -> rowptr & cursor ----------------
__global__ __launch_bounds__(256) void scan_block(
    const int* __restrict__ cnt, const int* __restrict__ partials,
    int* __restrict__ rowptr, int* __restrict__ cursor, int n)
{
  __shared__ int tsum[256];
  int base = blockIdx.x * SCAN_BS;
  int i0 = base + threadIdx.x * 4;
  int v[4];
  int local = 0;
  #pragma unroll
  for (int k = 0; k < 4; ++k) { int g = i0 + k; v[k] = (g < n) ? cnt[g] : 0; local += v[k]; }
  tsum[threadIdx.x] = local;
  __syncthreads();
  for (int off = 1; off < 256; off <<= 1) {
    int y = (threadIdx.x >= off) ? tsum[threadIdx.x - off] : 0;
    __syncthreads();
    tsum[threadIdx.x] += y;
    __syncthreads();
  }
  int excl = tsum[threadIdx.x] - local;
  int pref = partials[blockIdx.x] + excl;
  #pragma unroll
  for (int k = 0; k < 4; ++k) {
    int g = i0 + k;
    if (g < n) {
      rowptr[g] = pref; cursor[g] = pref;
      pref += v[k];
      if (g == n - 1) rowptr[n] = pref;
    }
  }
}

// ---------------- CSR build: scatter src ids into slots ----------------
__global__ __launch_bounds__(256) void scatter_src(
    const int* __restrict__ src, const int* __restrict__ dst,
    int* __restrict__ cursor, int* __restrict__ col, int E)
{
  int e = blockIdx.x * 256 + threadIdx.x;
  if (e < E) {
    int p = atomicAdd(&cursor[dst[e]], 1);
    col[p] = src[e];
  }
}

// ---------------- GIN aggregate (gather): A[i] = b1 + P[i] + sum_{j->i} P[j] ----------------
__global__ __launch_bounds__(256) void gin_gather(
    const int* __restrict__ rowptr, const int* __restrict__ col,
    const float* __restrict__ P, const float* __restrict__ b1,
    float* __restrict__ A, int N)
{
  int node = blockIdx.x * 4 + (threadIdx.x >> 6);
  int c = threadIdx.x & 63;
  if (node >= N) return;
  int beg = rowptr[node], end = rowptr[node + 1];
  float acc = P[(long long)node * 64 + c] + b1[c];
  int j = beg;
  for (; j + 3 < end; j += 4) {
    int s0 = col[j], s1 = col[j + 1], s2 = col[j + 2], s3 = col[j + 3];
    float a0 = P[(long long)s0 * 64 + c];
    float a1 = P[(long long)s1 * 64 + c];
    float a2 = P[(long long)s2 * 64 + c];
    float a3 = P[(long long)s3 * 64 + c];
    acc += a0; acc += a1; acc += a2; acc += a3;
  }
  for (; j < end; ++j) acc += P[(long long)col[j] * 64 + c];
  A[(long long)node * 64 + c] = acc;
}

// ---------------- BN stats: sum / sumsq of relu(A) per column ----------------
__global__ __launch_bounds__(256) void bn_stats(
    const float* __restrict__ A, float* __restrict__ stats, int M)
{
  const int c = threadIdx.x & 63;
  const int r = threadIdx.x >> 6;
  float s = 0.f, s2 = 0.f;
  for (long long row = (long long)blockIdx.x * 4 + r; row < M; row += (long long)gridDim.x * 4) {
    float v = fmaxf(A[row * 64 + c], 0.f);
    s += v; s2 += v * v;
  }
  __shared__ float red[2][4][64];
  red[0][r][c] = s; red[1][r][c] = s2;
  __syncthreads();
  if (r == 0) {
    s  = red[0][0][c] + red[0][1][c] + red[0][2][c] + red[0][3][c];
    s2 = red[1][0][c] + red[1][1][c] + red[1][2][c] + red[1][3][c];
    atomicAdd(&stats[c], s);
    atomicAdd(&stats[64 + c], s2);
  }
}

// ---------------- fold BN into W2/b2 ----------------
__global__ void bn_fold(
    const float* __restrict__ stats, const float* __restrict__ g, const float* __restrict__ be,
    const float* __restrict__ W2, const float* __restrict__ b2,
    float* __restrict__ W2f, float* __restrict__ b2f, float invN)
{
  int j = threadIdx.x;  // 0..63
  __shared__ float sc[64], sh[64];
  float mu = stats[j] * invN;
  float var = stats[64 + j] * invN - mu * mu;
  float s = g[j] * rsqrtf(var + 1e-5f);
  sc[j] = s;
  sh[j] = be[j] - mu * s;
  __syncthreads();
  float acc = b2[j];
  for (int k = 0; k < 64; ++k) {
    float w = W2[k * 64 + j];
    W2f[k * 64 + j] = sc[k] * w;
    acc += sh[k] * w;
  }
  b2f[j] = acc;
}

// ---------------- global add pool over sorted batch: one wave per graph ----------------
__global__ __launch_bounds__(256) void pool_sorted(
    const float* __restrict__ Hf, const int* __restrict__ batch,
    float* __restrict__ out, int N, int G)
{
  int g = blockIdx.x * 4 + (threadIdx.x >> 6);
  int c = threadIdx.x & 63;
  if (g >= G) return;
  int lo = 0, hi = N;
  while (lo < hi) { int mid = (lo + hi) >> 1; if (batch[mid] < g) lo = mid + 1; else hi = mid; }
  int beg = lo;
  hi = N;
  while (lo < hi) { int mid = (lo + hi) >> 1; if (batch[mid] < g + 1) lo = mid + 1; else hi = mid; }
  int end = lo;
  float acc = 0.f;
  for (int r = beg; r < end; ++r) acc += Hf[(long long)r * 64 + c];
  out[(long long)g * 64 + c] = acc;
}

extern "C" void kernel_launch(void* const* d_in, const int* in_sizes, int n_in,
                              void* d_out, int out_size, void* d_ws, size_t ws_size,
                              hipStream_t stream) {
  const float* x      = (const float*)d_in[0];
  const int*   ei     = (const int*)d_in[1];
  const int*   batch  = (const int*)d_in[2];
  const float* W1_0 = (const float*)d_in[3];
  const float* b1_0 = (const float*)d_in[4];
  const float* g_0  = (const float*)d_in[5];
  const float* be_0 = (const float*)d_in[6];
  const float* W2_0 = (const float*)d_in[7];
  const float* b2_0 = (const float*)d_in[8];
  const float* W1_1 = (const float*)d_in[9];
  const float* b1_1 = (const float*)d_in[10];
  const float* g_1  = (const float*)d_in[11];
  const float* be_1 = (const float*)d_in[12];
  const float* W2_1 = (const float*)d_in[13];
  const float* b2_1 = (const float*)d_in[14];

  const int N = in_sizes[0] / 128;
  const int E = in_sizes[1] / 2;
  const int G = (out_size - N * 64) / 64;
  const int* srcI = ei;
  const int* dstI = ei + E;

  float* outG = (float*)d_out;                       // [G,64]
  float* outH = (float*)d_out + (long long)G * 64;   // [N,64]

  // ---- workspace layout ----
  float* ws0    = (float*)d_ws;                      // [N,64] scratch (25.6 MB)
  float* stats0 = ws0 + (long long)N * 64;           // 128
  float* stats1 = stats0 + 128;                      // 128
  float* W2f0   = stats1 + 128;                      // 4096
  float* b2f0   = W2f0 + 64 * 64;                    // 64
  float* W2f1   = b2f0 + 64;                         // 4096
  float* b2f1   = W2f1 + 64 * 64;                    // 64
  int* cnt      = (int*)(b2f1 + 64);                 // N+1
  int* rowptr   = cnt + (N + 1);                     // N+1
  int* cursor   = rowptr + (N + 1);                  // N
  int* partials = cursor + N;                        // <=128
  int* col      = partials + 128;                    // E (12.8 MB)

  const int nb = cdiv_ll(N, SCAN_BS);
  const int eGrid = cdiv_ll(E, 256);
  const int gemmGrid = 2048;
  const int nodeGrid = cdiv_ll(N, 4);

  hipMemsetAsync(cnt, 0, (long long)(N + 1) * sizeof(int), stream);
  hipMemsetAsync(stats0, 0, 256 * sizeof(float), stream);

  // ---- CSR build (shared by both layers) ----
  hist_dst<<<eGrid, 256, 0, stream>>>(dstI, cnt, E);
  scan_partial_sums<<<nb, 256, 0, stream>>>(cnt, partials, N);
  scan_scan_partials<<<1, 64, 0, stream>>>(partials, nb);
  scan_block<<<nb, 256, 0, stream>>>(cnt, partials, rowptr, cursor, N);
  scatter_src<<<eGrid, 256, 0, stream>>>(srcI, dstI, cursor, col, E);

  // ---- layer 0 ----
  gemm_n64<128, false, false, false><<<gemmGrid, 256, 0, stream>>>(x, W1_0, nullptr, ws0, N);
  gin_gather<<<nodeGrid, 256, 0, stream>>>(rowptr, col, ws0, b1_0, outH, N);
  bn_stats<<<256, 256, 0, stream>>>(outH, stats0, N);
  bn_fold<<<1, 64, 0, stream>>>(stats0, g_0, be_0, W2_0, b2_0, W2f0, b2f0, 1.0f / N);
  gemm_n64<64, true, true, true><<<gemmGrid, 256, 0, stream>>>(outH, W2f0, b2f0, ws0, N);

  // ---- layer 1 ----
  gemm_n64<64, false, false, false><<<gemmGrid, 256, 0, stream>>>(ws0, W1_1, nullptr, outH, N);
  gin_gather<<<nodeGrid, 256, 0, stream>>>(rowptr, col, outH, b1_1, ws0, N);
  bn_stats<<<256, 256, 0, stream>>>(ws0, stats1, N);
  bn_fold<<<1, 64, 0, stream>>>(stats1, g_1, be_1, W2_1, b2_1, W2f1, b2f1, 1.0f / N);
  gemm_n64<64, true, true, true><<<gemmGrid, 256, 0, stream>>>(ws0, W2f1, b2f1, outH, N);

  // ---- global add pool (sorted batch, no atomics) ----
  pool_sorted<<<cdiv_ll(G, 4), 256, 0, stream>>>(outH, batch, outG, N, G);
}

// Round 3
// 624.094 us; speedup vs baseline: 9.3087x; 1.5453x over previous
//
#include <hip/hip_runtime.h>

static inline int cdiv_ll(long long a, long long b){ return (int)((a + b - 1) / b); }

#define EB_CHUNK 4096   // edges per partition block
#define NPB 256         // nodes per bucket (pow2: bucket = dst >> 8)
#define MAXNB 512       // max buckets supported in LDS

// ---------------- GEMM: Y[M,64] = op(X[M,K]) @ W[K,64] (+bias) (+relu) ----------------
template<int K, bool RELU_IN, bool RELU_OUT, bool BIAS>
__global__ __launch_bounds__(256) void gemm_n64(
    const float* __restrict__ X, const float* __restrict__ W,
    const float* __restrict__ bias, float* __restrict__ Y, int M)
{
  __shared__ float Wl[K * 64];
  __shared__ float Xl[4][K];
  for (int i = threadIdx.x; i < K * 16; i += 256)
    reinterpret_cast<float4*>(Wl)[i] = reinterpret_cast<const float4*>(W)[i];
  const int c = threadIdx.x & 63;
  const int r = threadIdx.x >> 6;
  const float bv = BIAS ? bias[c] : 0.0f;

  for (long long rb = (long long)blockIdx.x * 4; rb < M; rb += (long long)gridDim.x * 4) {
    __syncthreads();
    for (int i = threadIdx.x; i < K; i += 256) {
      int rr = i / (K / 4), kk = i % (K / 4);
      if (rb + rr < M) {
        float4 v = reinterpret_cast<const float4*>(X + (rb + rr) * K)[kk];
        if (RELU_IN) {
          v.x = fmaxf(v.x, 0.f); v.y = fmaxf(v.y, 0.f);
          v.z = fmaxf(v.z, 0.f); v.w = fmaxf(v.w, 0.f);
        }
        reinterpret_cast<float4*>(&Xl[rr][0])[kk] = v;
      }
    }
    __syncthreads();
    if (rb + r < M) {
      float acc = 0.f;
      #pragma unroll
      for (int k = 0; k < K; ++k) acc = fmaf(Xl[r][k], Wl[k * 64 + c], acc);
      float o = acc + bv;
      if (RELU_OUT) o = fmaxf(o, 0.f);
      Y[(rb + r) * 64 + c] = o;
    }
  }
}

// ---------------- partition pass 1: per-block bucket histogram (LDS, no global atomics) ----
__global__ __launch_bounds__(256) void part_hist(
    const int* __restrict__ dst, int* __restrict__ blockHist,
    int E, int NB, int nblocksB)
{
  __shared__ int hist[MAXNB];
  for (int i = threadIdx.x; i < NB; i += 256) hist[i] = 0;
  __syncthreads();
  int base = blockIdx.x * EB_CHUNK;
  int end = min(base + EB_CHUNK, E);
  for (int e = base + threadIdx.x; e < end; e += 256)
    atomicAdd(&hist[dst[e] >> 8], 1);
  __syncthreads();
  for (int i = threadIdx.x; i < NB; i += 256)
    blockHist[(long long)i * nblocksB + blockIdx.x] = hist[i];
}

// ---------------- scan blockHist within each bucket (one block per bucket) ----------------
__global__ __launch_bounds__(256) void scan_bucket_blocks(
    int* __restrict__ blockHist, int* __restrict__ bucketTotal, int nblocksB)
{
  int* row = blockHist + (long long)blockIdx.x * nblocksB;
  __shared__ int tsum[256];
  int v[4]; int local = 0;
  int i0 = threadIdx.x * 4;                 // supports nblocksB <= 1024
  #pragma unroll
  for (int k = 0; k < 4; ++k) { int g = i0 + k; v[k] = (g < nblocksB) ? row[g] : 0; local += v[k]; }
  tsum[threadIdx.x] = local;
  __syncthreads();
  for (int off = 1; off < 256; off <<= 1) {
    int y = (threadIdx.x >= off) ? tsum[threadIdx.x - off] : 0;
    __syncthreads();
    tsum[threadIdx.x] += y;
    __syncthreads();
  }
  int pref = tsum[threadIdx.x] - local;     // exclusive prefix of this thread's chunk
  #pragma unroll
  for (int k = 0; k < 4; ++k) { int g = i0 + k; if (g < nblocksB) { row[g] = pref; pref += v[k]; } }
  if (threadIdx.x == 255) bucketTotal[blockIdx.x] = tsum[255];
}

// ---------------- exclusive scan of bucket totals (single block) ----------------
__global__ __launch_bounds__(512) void scan_buckets(
    const int* __restrict__ bucketTotal, int* __restrict__ bucketBase, int NB)
{
  __shared__ int tsum[512];
  int t = threadIdx.x;
  int v = (t < NB) ? bucketTotal[t] : 0;
  tsum[t] = v;
  __syncthreads();
  for (int off = 1; off < 512; off <<= 1) {
    int y = (t >= off) ? tsum[t - off] : 0;
    __syncthreads();
    tsum[t] += y;
    __syncthreads();
  }
  if (t < NB) bucketBase[t] = tsum[t] - v;
  if (t == NB - 1) bucketBase[NB] = tsum[t];
}

// ---------------- partition pass 2: scatter packed (src | localDst<<24) into bucket runs ----
__global__ __launch_bounds__(256) void part_scatter(
    const int* __restrict__ src, const int* __restrict__ dst,
    const int* __restrict__ blockHist, const int* __restrict__ bucketBase,
    unsigned* __restrict__ ebuf, int E, int NB, int nblocksB)
{
  __shared__ int cursor[MAXNB];
  for (int i = threadIdx.x; i < NB; i += 256)
    cursor[i] = bucketBase[i] + blockHist[(long long)i * nblocksB + blockIdx.x];
  __syncthreads();
  int base = blockIdx.x * EB_CHUNK;
  int end = min(base + EB_CHUNK, E);
  for (int e = base + threadIdx.x; e < end; e += 256) {
    int s = src[e], d = dst[e];
    int p = atomicAdd(&cursor[d >> 8], 1);
    ebuf[p] = (unsigned)s | ((unsigned)(d & (NPB - 1)) << 24);
  }
}

// ---------------- per-bucket counting sort -> rowptr + col (one block per bucket) ----------
__global__ __launch_bounds__(256) void bucket_csr(
    const unsigned* __restrict__ ebuf, const int* __restrict__ bucketBase,
    int* __restrict__ rowptr, int* __restrict__ col, int N, int NB)
{
  int b = blockIdx.x;
  int eb = bucketBase[b], ee = bucketBase[b + 1];
  int nodeBase = b * NPB;
  __shared__ int hist[NPB];
  __shared__ int tsum[NPB];
  __shared__ int cur[NPB];
  hist[threadIdx.x] = 0;
  __syncthreads();
  for (int e = eb + threadIdx.x; e < ee; e += 256)
    atomicAdd(&hist[ebuf[e] >> 24], 1);
  __syncthreads();
  int local = hist[threadIdx.x];
  tsum[threadIdx.x] = local;
  __syncthreads();
  for (int off = 1; off < 256; off <<= 1) {
    int y = (threadIdx.x >= off) ? tsum[threadIdx.x - off] : 0;
    __syncthreads();
    tsum[threadIdx.x] += y;
    __syncthreads();
  }
  int pref = tsum[threadIdx.x] - local;     // exclusive
  int node = nodeBase + threadIdx.x;
  if (node < N) rowptr[node] = eb + pref;
  if (b == NB - 1 && threadIdx.x == 0) rowptr[N] = ee;
  cur[threadIdx.x] = pref;
  __syncthreads();
  for (int e = eb + threadIdx.x; e < ee; e += 256) {
    unsigned w = ebuf[e];
    int l = (int)(w >> 24);
    int p = eb + atomicAdd(&cur[l], 1);
    col[p] = (int)(w & 0xFFFFFFu);
  }
}

// ---------------- GIN aggregate (gather): A[i] = b1 + P[i] + sum_{j->i} P[j] ----------------
__global__ __launch_bounds__(256) void gin_gather(
    const int* __restrict__ rowptr, const int* __restrict__ col,
    const float* __restrict__ P, const float* __restrict__ b1,
    float* __restrict__ A, int N)
{
  int node = blockIdx.x * 4 + (threadIdx.x >> 6);
  int c = threadIdx.x & 63;
  if (node >= N) return;
  int beg = rowptr[node], end = rowptr[node + 1];
  float acc = P[(long long)node * 64 + c] + b1[c];
  int j = beg;
  for (; j + 3 < end; j += 4) {
    int s0 = col[j], s1 = col[j + 1], s2 = col[j + 2], s3 = col[j + 3];
    float a0 = P[(long long)s0 * 64 + c];
    float a1 = P[(long long)s1 * 64 + c];
    float a2 = P[(long long)s2 * 64 + c];
    float a3 = P[(long long)s3 * 64 + c];
    acc += a0; acc += a1; acc += a2; acc += a3;
  }
  for (; j < end; ++j) acc += P[(long long)col[j] * 64 + c];
  A[(long long)node * 64 + c] = acc;
}

// ---------------- BN stats: sum / sumsq of relu(A) per column ----------------
__global__ __launch_bounds__(256) void bn_stats(
    const float* __restrict__ A, float* __restrict__ stats, int M)
{
  const int c = threadIdx.x & 63;
  const int r = threadIdx.x >> 6;
  float s = 0.f, s2 = 0.f;
  for (long long row = (long long)blockIdx.x * 4 + r; row < M; row += (long long)gridDim.x * 4) {
    float v = fmaxf(A[row * 64 + c], 0.f);
    s += v; s2 += v * v;
  }
  __shared__ float red[2][4][64];
  red[0][r][c] = s; red[1][r][c] = s2;
  __syncthreads();
  if (r == 0) {
    s  = red[0][0][c] + red[0][1][c] + red[0][2][c] + red[0][3][c];
    s2 = red[1][0][c] + red[1][1][c] + red[1][2][c] + red[1][3][c];
    atomicAdd(&stats[c], s);
    atomicAdd(&stats[64 + c], s2);
  }
}

// ---------------- fold BN into W2/b2 ----------------
__global__ void bn_fold(
    const float* __restrict__ stats, const float* __restrict__ g, const float* __restrict__ be,
    const float* __restrict__ W2, const float* __restrict__ b2,
    float* __restrict__ W2f, float* __restrict__ b2f, float invN)
{
  int j = threadIdx.x;  // 0..63
  __shared__ float sc[64], sh[64];
  float mu = stats[j] * invN;
  float var = stats[64 + j] * invN - mu * mu;
  float s = g[j] * rsqrtf(var + 1e-5f);
  sc[j] = s;
  sh[j] = be[j] - mu * s;
  __syncthreads();
  float acc = b2[j];
  for (int k = 0; k < 64; ++k) {
    float w = W2[k * 64 + j];
    W2f[k * 64 + j] = sc[k] * w;
    acc += sh[k] * w;
  }
  b2f[j] = acc;
}

// ---------------- global add pool over sorted batch: one wave per graph ----------------
__global__ __launch_bounds__(256) void pool_sorted(
    const float* __restrict__ Hf, const int* __restrict__ batch,
    float* __restrict__ out, int N, int G)
{
  int g = blockIdx.x * 4 + (threadIdx.x >> 6);
  int c = threadIdx.x & 63;
  if (g >= G) return;
  int lo = 0, hi = N;
  while (lo < hi) { int mid = (lo + hi) >> 1; if (batch[mid] < g) lo = mid + 1; else hi = mid; }
  int beg = lo;
  hi = N;
  while (lo < hi) { int mid = (lo + hi) >> 1; if (batch[mid] < g + 1) lo = mid + 1; else hi = mid; }
  int end = lo;
  float acc = 0.f;
  for (int r = beg; r < end; ++r) acc += Hf[(long long)r * 64 + c];
  out[(long long)g * 64 + c] = acc;
}

extern "C" void kernel_launch(void* const* d_in, const int* in_sizes, int n_in,
                              void* d_out, int out_size, void* d_ws, size_t ws_size,
                              hipStream_t stream) {
  const float* x      = (const float*)d_in[0];
  const int*   ei     = (const int*)d_in[1];
  const int*   batch  = (const int*)d_in[2];
  const float* W1_0 = (const float*)d_in[3];
  const float* b1_0 = (const float*)d_in[4];
  const float* g_0  = (const float*)d_in[5];
  const float* be_0 = (const float*)d_in[6];
  const float* W2_0 = (const float*)d_in[7];
  const float* b2_0 = (const float*)d_in[8];
  const float* W1_1 = (const float*)d_in[9];
  const float* b1_1 = (const float*)d_in[10];
  const float* g_1  = (const float*)d_in[11];
  const float* be_1 = (const float*)d_in[12];
  const float* W2_1 = (const float*)d_in[13];
  const float* b2_1 = (const float*)d_in[14];

  const int N = in_sizes[0] / 128;
  const int E = in_sizes[1] / 2;
  const int G = (out_size - N * 64) / 64;
  const int* srcI = ei;
  const int* dstI = ei + E;

  float* outG = (float*)d_out;                       // [G,64]
  float* outH = (float*)d_out + (long long)G * 64;   // [N,64]

  const int NB = cdiv_ll(N, NPB);                    // buckets (391 for N=100K)
  const int nblocksB = cdiv_ll(E, EB_CHUNK);         // partition blocks (782)

  // ---- workspace layout ----
  float* ws0    = (float*)d_ws;                      // [N,64] scratch (25.6 MB)
  unsigned* ebuf = (unsigned*)d_ws;                  // [E] packed, ALIASES ws0 (disjoint lifetime)
  float* stats0 = ws0 + (long long)N * 64;           // 128
  float* stats1 = stats0 + 128;                      // 128
  float* W2f0   = stats1 + 128;                      // 4096
  float* b2f0   = W2f0 + 64 * 64;                    // 64
  float* W2f1   = b2f0 + 64;                         // 4096
  float* b2f1   = W2f1 + 64 * 64;                    // 64
  int* col      = (int*)(b2f1 + 64);                 // E
  int* rowptr   = col + E;                           // N+1
  int* blockHist= rowptr + (N + 1);                  // NB*nblocksB
  int* bucketTotal = blockHist + (long long)NB * nblocksB;  // NB
  int* bucketBase  = bucketTotal + NB;               // NB+1

  const int gemmGrid = 2048;
  const int nodeGrid = cdiv_ll(N, 4);

  hipMemsetAsync(stats0, 0, 256 * sizeof(float), stream);

  // ---- CSR build (bucket partition; no global atomics) ----
  part_hist<<<nblocksB, 256, 0, stream>>>(dstI, blockHist, E, NB, nblocksB);
  scan_bucket_blocks<<<NB, 256, 0, stream>>>(blockHist, bucketTotal, nblocksB);
  scan_buckets<<<1, 512, 0, stream>>>(bucketTotal, bucketBase, NB);
  part_scatter<<<nblocksB, 256, 0, stream>>>(srcI, dstI, blockHist, bucketBase, ebuf, E, NB, nblocksB);
  bucket_csr<<<NB, 256, 0, stream>>>(ebuf, bucketBase, rowptr, col, N, NB);

  // ---- layer 0 ----
  gemm_n64<128, false, false, false><<<gemmGrid, 256, 0, stream>>>(x, W1_0, nullptr, ws0, N);
  gin_gather<<<nodeGrid, 256, 0, stream>>>(rowptr, col, ws0, b1_0, outH, N);
  bn_stats<<<256, 256, 0, stream>>>(outH, stats0, N);
  bn_fold<<<1, 64, 0, stream>>>(stats0, g_0, be_0, W2_0, b2_0, W2f0, b2f0, 1.0f / N);
  gemm_n64<64, true, true, true><<<gemmGrid, 256, 0, stream>>>(outH, W2f0, b2f0, ws0, N);

  // ---- layer 1 ----
  gemm_n64<64, false, false, false><<<gemmGrid, 256, 0, stream>>>(ws0, W1_1, nullptr, outH, N);
  gin_gather<<<nodeGrid, 256, 0, stream>>>(rowptr, col, outH, b1_1, ws0, N);
  bn_stats<<<256, 256, 0, stream>>>(ws0, stats1, N);
  bn_fold<<<1, 64, 0, stream>>>(stats1, g_1, be_1, W2_1, b2_1, W2f1, b2f1, 1.0f / N);
  gemm_n64<64, true, true, true><<<gemmGrid, 256, 0, stream>>>(ws0, W2f1, b2f1, outH, N);

  // ---- global add pool (sorted batch, no atomics) ----
  pool_sorted<<<cdiv_ll(G, 4), 256, 0, stream>>>(outH, batch, outG, N, G);
}

// Round 4
// 620.358 us; speedup vs baseline: 9.3648x; 1.0060x over previous
//
#include <hip/hip_runtime.h>

static inline int cdiv_ll(long long a, long long b){ return (int)((a + b - 1) / b); }

#define EB_CHUNK 4096   // edges per partition block
#define NPB 256         // nodes per bucket (pow2: bucket = dst >> 8)
#define MAXNB 512       // max buckets supported in LDS

__device__ __forceinline__ float bf2f(unsigned short h) {
  unsigned u = (unsigned)h << 16;
  return __uint_as_float(u);
}
__device__ __forceinline__ unsigned short f2bf(float f) {
  unsigned u = __float_as_uint(f);
  u += 0x7FFF + ((u >> 16) & 1);   // round-to-nearest-even
  return (unsigned short)(u >> 16);
}

// ---------------- GEMM: Y[M,64] = op(X[M,K]) @ W[K,64] (+bias)(+relu), 4x4 register tile ----
// X: fp32 or bf16 (IN_BF16). Y: fp32 or bf16 (OUT_BF16). Block computes 64 rows x 64 cols.
template<int K, bool IN_BF16, bool RELU_IN, bool RELU_OUT, bool BIAS, bool OUT_BF16>
__global__ __launch_bounds__(256) void gemm64x64(
    const void* __restrict__ Xv, const float* __restrict__ W,
    const float* __restrict__ bias, void* __restrict__ Yv, int M)
{
  __shared__ float Wl[K * 64];
  __shared__ float XT[64 * 68];   // [k][row], stride 68 to break bank alignment
  const float* Xf = (const float*)Xv;
  const unsigned short* Xh = (const unsigned short*)Xv;

  for (int i = threadIdx.x; i < K * 16; i += 256)
    reinterpret_cast<float4*>(Wl)[i] = reinterpret_cast<const float4*>(W)[i];

  const int tr = threadIdx.x >> 4;   // 0..15 -> rows 4tr..4tr+3
  const int tc = threadIdx.x & 15;   // 0..15 -> cols 4tc..4tc+3
  const long long rb = (long long)blockIdx.x * 64;

  float acc[4][4] = {};

  for (int ch = 0; ch < K / 64; ++ch) {
    const int c0 = ch * 64;
    __syncthreads();   // protect XT reuse (and cover Wl on first iter)
    for (int f = threadIdx.x; f < 1024; f += 256) {
      int r = f >> 4, k0 = (f & 15) * 4;
      float4 v = make_float4(0.f, 0.f, 0.f, 0.f);
      if (rb + r < M) {
        if (IN_BF16) {
          ushort4 h = *reinterpret_cast<const ushort4*>(Xh + (rb + r) * K + c0 + k0);
          v.x = bf2f(h.x); v.y = bf2f(h.y); v.z = bf2f(h.z); v.w = bf2f(h.w);
        } else {
          v = *reinterpret_cast<const float4*>(Xf + (rb + r) * K + c0 + k0);
        }
        if (RELU_IN) {
          v.x = fmaxf(v.x, 0.f); v.y = fmaxf(v.y, 0.f);
          v.z = fmaxf(v.z, 0.f); v.w = fmaxf(v.w, 0.f);
        }
      }
      XT[(k0 + 0) * 68 + r] = v.x;
      XT[(k0 + 1) * 68 + r] = v.y;
      XT[(k0 + 2) * 68 + r] = v.z;
      XT[(k0 + 3) * 68 + r] = v.w;
    }
    __syncthreads();
    #pragma unroll 8
    for (int k = 0; k < 64; ++k) {
      float4 xa = *reinterpret_cast<const float4*>(&XT[k * 68 + 4 * tr]);
      float4 wb = *reinterpret_cast<const float4*>(&Wl[(c0 + k) * 64 + 4 * tc]);
      acc[0][0] = fmaf(xa.x, wb.x, acc[0][0]); acc[0][1] = fmaf(xa.x, wb.y, acc[0][1]);
      acc[0][2] = fmaf(xa.x, wb.z, acc[0][2]); acc[0][3] = fmaf(xa.x, wb.w, acc[0][3]);
      acc[1][0] = fmaf(xa.y, wb.x, acc[1][0]); acc[1][1] = fmaf(xa.y, wb.y, acc[1][1]);
      acc[1][2] = fmaf(xa.y, wb.z, acc[1][2]); acc[1][3] = fmaf(xa.y, wb.w, acc[1][3]);
      acc[2][0] = fmaf(xa.z, wb.x, acc[2][0]); acc[2][1] = fmaf(xa.z, wb.y, acc[2][1]);
      acc[2][2] = fmaf(xa.z, wb.z, acc[2][2]); acc[2][3] = fmaf(xa.z, wb.w, acc[2][3]);
      acc[3][0] = fmaf(xa.w, wb.x, acc[3][0]); acc[3][1] = fmaf(xa.w, wb.y, acc[3][1]);
      acc[3][2] = fmaf(xa.w, wb.z, acc[3][2]); acc[3][3] = fmaf(xa.w, wb.w, acc[3][3]);
    }
  }

  float4 bb = make_float4(0.f, 0.f, 0.f, 0.f);
  if (BIAS) bb = *reinterpret_cast<const float4*>(bias + 4 * tc);
  #pragma unroll
  for (int rr = 0; rr < 4; ++rr) {
    long long row = rb + 4 * tr + rr;
    if (row < M) {
      float4 o = make_float4(acc[rr][0] + bb.x, acc[rr][1] + bb.y,
                             acc[rr][2] + bb.z, acc[rr][3] + bb.w);
      if (RELU_OUT) {
        o.x = fmaxf(o.x, 0.f); o.y = fmaxf(o.y, 0.f);
        o.z = fmaxf(o.z, 0.f); o.w = fmaxf(o.w, 0.f);
      }
      if (OUT_BF16) {
        ushort4 h; h.x = f2bf(o.x); h.y = f2bf(o.y); h.z = f2bf(o.z); h.w = f2bf(o.w);
        *reinterpret_cast<ushort4*>((unsigned short*)Yv + row * 64 + 4 * tc) = h;
      } else {
        *reinterpret_cast<float4*>((float*)Yv + row * 64 + 4 * tc) = o;
      }
    }
  }
}

// ---------------- partition pass 1: per-block bucket histogram ----------------
__global__ __launch_bounds__(256) void part_hist(
    const int* __restrict__ dst, int* __restrict__ blockHist,
    int E, int NB, int nblocksB)
{
  __shared__ int hist[MAXNB];
  for (int i = threadIdx.x; i < NB; i += 256) hist[i] = 0;
  __syncthreads();
  int base = blockIdx.x * EB_CHUNK;
  int end = min(base + EB_CHUNK, E);
  for (int e = base + threadIdx.x; e < end; e += 256)
    atomicAdd(&hist[dst[e] >> 8], 1);
  __syncthreads();
  for (int i = threadIdx.x; i < NB; i += 256)
    blockHist[(long long)i * nblocksB + blockIdx.x] = hist[i];
}

// ---------------- scan blockHist within each bucket ----------------
__global__ __launch_bounds__(256) void scan_bucket_blocks(
    int* __restrict__ blockHist, int* __restrict__ bucketTotal, int nblocksB)
{
  int* row = blockHist + (long long)blockIdx.x * nblocksB;
  __shared__ int tsum[256];
  int v[4]; int local = 0;
  int i0 = threadIdx.x * 4;
  #pragma unroll
  for (int k = 0; k < 4; ++k) { int g = i0 + k; v[k] = (g < nblocksB) ? row[g] : 0; local += v[k]; }
  tsum[threadIdx.x] = local;
  __syncthreads();
  for (int off = 1; off < 256; off <<= 1) {
    int y = (threadIdx.x >= off) ? tsum[threadIdx.x - off] : 0;
    __syncthreads();
    tsum[threadIdx.x] += y;
    __syncthreads();
  }
  int pref = tsum[threadIdx.x] - local;
  #pragma unroll
  for (int k = 0; k < 4; ++k) { int g = i0 + k; if (g < nblocksB) { row[g] = pref; pref += v[k]; } }
  if (threadIdx.x == 255) bucketTotal[blockIdx.x] = tsum[255];
}

// ---------------- exclusive scan of bucket totals ----------------
__global__ __launch_bounds__(512) void scan_buckets(
    const int* __restrict__ bucketTotal, int* __restrict__ bucketBase, int NB)
{
  __shared__ int tsum[512];
  int t = threadIdx.x;
  int v = (t < NB) ? bucketTotal[t] : 0;
  tsum[t] = v;
  __syncthreads();
  for (int off = 1; off < 512; off <<= 1) {
    int y = (t >= off) ? tsum[t - off] : 0;
    __syncthreads();
    tsum[t] += y;
    __syncthreads();
  }
  if (t < NB) bucketBase[t] = tsum[t] - v;
  if (t == NB - 1) bucketBase[NB] = tsum[t];
}

// ---------------- partition pass 2: scatter packed (src | localDst<<24) ----------------
__global__ __launch_bounds__(256) void part_scatter(
    const int* __restrict__ src, const int* __restrict__ dst,
    const int* __restrict__ blockHist, const int* __restrict__ bucketBase,
    unsigned* __restrict__ ebuf, int E, int NB, int nblocksB)
{
  __shared__ int cursor[MAXNB];
  for (int i = threadIdx.x; i < NB; i += 256)
    cursor[i] = bucketBase[i] + blockHist[(long long)i * nblocksB + blockIdx.x];
  __syncthreads();
  int base = blockIdx.x * EB_CHUNK;
  int end = min(base + EB_CHUNK, E);
  for (int e = base + threadIdx.x; e < end; e += 256) {
    int s = src[e], d = dst[e];
    int p = atomicAdd(&cursor[d >> 8], 1);
    ebuf[p] = (unsigned)s | ((unsigned)(d & (NPB - 1)) << 24);
  }
}

// ---------------- per-bucket counting sort -> rowptr + col ----------------
__global__ __launch_bounds__(256) void bucket_csr(
    const unsigned* __restrict__ ebuf, const int* __restrict__ bucketBase,
    int* __restrict__ rowptr, int* __restrict__ col, int N, int NB)
{
  int b = blockIdx.x;
  int eb = bucketBase[b], ee = bucketBase[b + 1];
  int nodeBase = b * NPB;
  __shared__ int hist[NPB];
  __shared__ int tsum[NPB];
  __shared__ int cur[NPB];
  hist[threadIdx.x] = 0;
  __syncthreads();
  for (int e = eb + threadIdx.x; e < ee; e += 256)
    atomicAdd(&hist[ebuf[e] >> 24], 1);
  __syncthreads();
  int local = hist[threadIdx.x];
  tsum[threadIdx.x] = local;
  __syncthreads();
  for (int off = 1; off < 256; off <<= 1) {
    int y = (threadIdx.x >= off) ? tsum[threadIdx.x - off] : 0;
    __syncthreads();
    tsum[threadIdx.x] += y;
    __syncthreads();
  }
  int pref = tsum[threadIdx.x] - local;
  int node = nodeBase + threadIdx.x;
  if (node < N) rowptr[node] = eb + pref;
  if (b == NB - 1 && threadIdx.x == 0) rowptr[N] = ee;
  cur[threadIdx.x] = pref;
  __syncthreads();
  for (int e = eb + threadIdx.x; e < ee; e += 256) {
    unsigned w = ebuf[e];
    int l = (int)(w >> 24);
    int p = eb + atomicAdd(&cur[l], 1);
    col[p] = (int)(w & 0xFFFFFFu);
  }
}

// ---- GIN aggregate (bf16 gather) + fused BN stats:
//      A[i] = b1 + P[i] + sum_{j->i} P[j];  stats += {relu(A), relu(A)^2}
__global__ __launch_bounds__(256) void gin_gather_bf16(
    const int* __restrict__ rowptr, const int* __restrict__ col,
    const unsigned short* __restrict__ P, const float* __restrict__ b1,
    float* __restrict__ A, float* __restrict__ stats, int N, int nodeStride)
{
  const int lane = threadIdx.x & 63;
  const int wv = threadIdx.x >> 6;   // wave in block (0..3)
  const int half = lane >> 5;        // 0: even edges + self, 1: odd edges
  const int cl = lane & 31;          // col pair index: cols 2cl, 2cl+1
  float s0 = 0.f, q0 = 0.f, s1 = 0.f, q1 = 0.f;

  for (int node = blockIdx.x * 4 + wv; node < N; node += nodeStride) {
    int beg = rowptr[node], end = rowptr[node + 1];
    float a0, a1;
    if (half == 0) {
      ushort2 h = *reinterpret_cast<const ushort2*>(P + (long long)node * 64 + 2 * cl);
      a0 = bf2f(h.x) + b1[2 * cl];
      a1 = bf2f(h.y) + b1[2 * cl + 1];
    } else { a0 = 0.f; a1 = 0.f; }
    int j = beg + half;
    for (; j + 2 < end; j += 4) {
      int sA = col[j], sB = col[j + 2];
      ushort2 hA = *reinterpret_cast<const ushort2*>(P + (long long)sA * 64 + 2 * cl);
      ushort2 hB = *reinterpret_cast<const ushort2*>(P + (long long)sB * 64 + 2 * cl);
      a0 += bf2f(hA.x); a1 += bf2f(hA.y);
      a0 += bf2f(hB.x); a1 += bf2f(hB.y);
    }
    if (j < end) {
      int sA = col[j];
      ushort2 hA = *reinterpret_cast<const ushort2*>(P + (long long)sA * 64 + 2 * cl);
      a0 += bf2f(hA.x); a1 += bf2f(hA.y);
    }
    a0 += __shfl_xor(a0, 32);
    a1 += __shfl_xor(a1, 32);
    if (half == 0) {
      *reinterpret_cast<float2*>(A + (long long)node * 64 + 2 * cl) = make_float2(a0, a1);
      float r0 = fmaxf(a0, 0.f), r1 = fmaxf(a1, 0.f);
      s0 += r0; q0 += r0 * r0; s1 += r1; q1 += r1 * r1;
    }
  }

  __shared__ float st[4][4][32];   // [wave][{s0,q0,s1,q1}][cl]
  if (half == 0) {
    st[wv][0][cl] = s0; st[wv][1][cl] = q0; st[wv][2][cl] = s1; st[wv][3][cl] = q1;
  }
  __syncthreads();
  if (threadIdx.x < 64) {
    int c = threadIdx.x;
    int cl2 = c >> 1, p = c & 1;
    int is = p ? 2 : 0, iq = p ? 3 : 1;
    float s = st[0][is][cl2] + st[1][is][cl2] + st[2][is][cl2] + st[3][is][cl2];
    float q = st[0][iq][cl2] + st[1][iq][cl2] + st[2][iq][cl2] + st[3][iq][cl2];
    atomicAdd(&stats[c], s);
    atomicAdd(&stats[64 + c], q);
  }
}

// ---------------- fold BN into W2/b2 ----------------
__global__ void bn_fold(
    const float* __restrict__ stats, const float* __restrict__ g, const float* __restrict__ be,
    const float* __restrict__ W2, const float* __restrict__ b2,
    float* __restrict__ W2f, float* __restrict__ b2f, float invN)
{
  int j = threadIdx.x;  // 0..63
  __shared__ float sc[64], sh[64];
  float mu = stats[j] * invN;
  float var = stats[64 + j] * invN - mu * mu;
  float s = g[j] * rsqrtf(var + 1e-5f);
  sc[j] = s;
  sh[j] = be[j] - mu * s;
  __syncthreads();
  float acc = b2[j];
  for (int k = 0; k < 64; ++k) {
    float w = W2[k * 64 + j];
    W2f[k * 64 + j] = sc[k] * w;
    acc += sh[k] * w;
  }
  b2f[j] = acc;
}

// ---------------- global add pool over sorted batch: one wave per graph ----------------
__global__ __launch_bounds__(256) void pool_sorted(
    const float* __restrict__ Hf, const int* __restrict__ batch,
    float* __restrict__ out, int N, int G)
{
  int g = blockIdx.x * 4 + (threadIdx.x >> 6);
  int c = threadIdx.x & 63;
  if (g >= G) return;
  int lo = 0, hi = N;
  while (lo < hi) { int mid = (lo + hi) >> 1; if (batch[mid] < g) lo = mid + 1; else hi = mid; }
  int beg = lo;
  hi = N;
  while (lo < hi) { int mid = (lo + hi) >> 1; if (batch[mid] < g + 1) lo = mid + 1; else hi = mid; }
  int end = lo;
  float acc = 0.f;
  for (int r = beg; r < end; ++r) acc += Hf[(long long)r * 64 + c];
  out[(long long)g * 64 + c] = acc;
}

extern "C" void kernel_launch(void* const* d_in, const int* in_sizes, int n_in,
                              void* d_out, int out_size, void* d_ws, size_t ws_size,
                              hipStream_t stream) {
  const float* x      = (const float*)d_in[0];
  const int*   ei     = (const int*)d_in[1];
  const int*   batch  = (const int*)d_in[2];
  const float* W1_0 = (const float*)d_in[3];
  const float* b1_0 = (const float*)d_in[4];
  const float* g_0  = (const float*)d_in[5];
  const float* be_0 = (const float*)d_in[6];
  const float* W2_0 = (const float*)d_in[7];
  const float* b2_0 = (const float*)d_in[8];
  const float* W1_1 = (const float*)d_in[9];
  const float* b1_1 = (const float*)d_in[10];
  const float* g_1  = (const float*)d_in[11];
  const float* be_1 = (const float*)d_in[12];
  const float* W2_1 = (const float*)d_in[13];
  const float* b2_1 = (const float*)d_in[14];

  const int N = in_sizes[0] / 128;
  const int E = in_sizes[1] / 2;
  const int G = (out_size - N * 64) / 64;
  const int* srcI = ei;
  const int* dstI = ei + E;

  float* outG = (float*)d_out;                       // [G,64]
  float* outH = (float*)d_out + (long long)G * 64;   // [N,64] fp32 (doubles as A buffer)

  const int NB = cdiv_ll(N, NPB);
  const int nblocksB = cdiv_ll(E, EB_CHUNK);

  // ---- workspace layout (~40 MB) ----
  char* w = (char*)d_ws;
  size_t r2 = (size_t)E * 4;                         // ebuf region; >= N*64*2 (P bf16)
  if ((size_t)N * 64 * 2 > r2) r2 = (size_t)N * 64 * 2;
  unsigned* ebuf        = (unsigned*)w;              // CSR-build only
  unsigned short* Pbuf  = (unsigned short*)w;        // bf16 P table (aliases ebuf; disjoint lifetime)
  w += r2;
  unsigned short* Hbuf  = (unsigned short*)w; w += (size_t)N * 64 * 2;  // h1 bf16
  int* col       = (int*)w; w += (size_t)E * 4;
  int* rowptr    = (int*)w; w += (size_t)(N + 1) * 4;
  int* blockHist = (int*)w; w += (size_t)NB * nblocksB * 4;
  int* bucketTotal = (int*)w; w += (size_t)NB * 4;
  int* bucketBase  = (int*)w; w += (size_t)(NB + 1) * 4;
  float* stats0 = (float*)w; w += 128 * 4;
  float* stats1 = (float*)w; w += 128 * 4;
  float* W2f0   = (float*)w; w += 64 * 64 * 4;
  float* b2f0   = (float*)w; w += 64 * 4;
  float* W2f1   = (float*)w; w += 64 * 64 * 4;
  float* b2f1   = (float*)w; w += 64 * 4;

  const int gemmGrid = cdiv_ll(N, 64);
  const int gatherGrid = 768;

  hipMemsetAsync(stats0, 0, 256 * sizeof(float), stream);  // stats0+stats1 contiguous

  // ---- CSR build (bucket partition; LDS atomics only) ----
  part_hist<<<nblocksB, 256, 0, stream>>>(dstI, blockHist, E, NB, nblocksB);
  scan_bucket_blocks<<<NB, 256, 0, stream>>>(blockHist, bucketTotal, nblocksB);
  scan_buckets<<<1, 512, 0, stream>>>(bucketTotal, bucketBase, NB);
  part_scatter<<<nblocksB, 256, 0, stream>>>(srcI, dstI, blockHist, bucketBase, ebuf, E, NB, nblocksB);
  bucket_csr<<<NB, 256, 0, stream>>>(ebuf, bucketBase, rowptr, col, N, NB);

  // ---- layer 0 ----
  // P0 = x @ W1_0 -> bf16 (ebuf now dead)
  gemm64x64<128, false, false, false, false, true><<<gemmGrid, 256, 0, stream>>>(x, W1_0, nullptr, Pbuf, N);
  // A0 = b1_0 + P0 + gather(P0); stats0 += relu stats   (A0 -> outH)
  gin_gather_bf16<<<gatherGrid, 256, 0, stream>>>(rowptr, col, Pbuf, b1_0, outH, stats0, N, gatherGrid * 4);
  bn_fold<<<1, 64, 0, stream>>>(stats0, g_0, be_0, W2_0, b2_0, W2f0, b2f0, 1.0f / N);
  // h1 = relu(relu(A0) @ W2f0 + b2f0) -> bf16 (Hbuf)
  gemm64x64<64, false, true, true, true, true><<<gemmGrid, 256, 0, stream>>>(outH, W2f0, b2f0, Hbuf, N);

  // ---- layer 1 ----
  // P1 = h1 @ W1_1 -> bf16 (Pbuf, P0 dead)
  gemm64x64<64, true, false, false, false, true><<<gemmGrid, 256, 0, stream>>>(Hbuf, W1_1, nullptr, Pbuf, N);
  // A1 = b1_1 + P1 + gather(P1); stats1   (A1 -> outH, A0 dead)
  gin_gather_bf16<<<gatherGrid, 256, 0, stream>>>(rowptr, col, Pbuf, b1_1, outH, stats1, N, gatherGrid * 4);
  bn_fold<<<1, 64, 0, stream>>>(stats1, g_1, be_1, W2_1, b2_1, W2f1, b2f1, 1.0f / N);
  // h2 = relu(relu(A1) @ W2f1 + b2f1) -> fp32, IN-PLACE in outH
  // (safe: K=64 single chunk -- block fully stages its 64 rows to LDS before storing)
  gemm64x64<64, false, true, true, true, false><<<gemmGrid, 256, 0, stream>>>(outH, W2f1, b2f1, outH, N);

  // ---- global add pool (sorted batch, no atomics) ----
  pool_sorted<<<cdiv_ll(G, 4), 256, 0, stream>>>(outH, batch, outG, N, G);
}

// Round 5
// 445.685 us; speedup vs baseline: 13.0350x; 1.3919x over previous
//
#include <hip/hip_runtime.h>

static inline int cdiv_ll(long long a, long long b){ return (int)((a + b - 1) / b); }

#define EB_CHUNK 8192   // edges per partition block
#define NPB 256         // nodes per bucket (pow2: bucket = dst >> 8)
#define MAXNB 512       // max buckets supported in LDS

__device__ __forceinline__ float bf2f(unsigned short h) {
  unsigned u = (unsigned)h << 16;
  return __uint_as_float(u);
}
__device__ __forceinline__ unsigned short f2bf(float f) {
  unsigned u = __float_as_uint(f);
  u += 0x7FFF + ((u >> 16) & 1);   // round-to-nearest-even
  return (unsigned short)(u >> 16);
}

// ---------------- GEMM: Y[M,64] = op(X[M,K]) @ W[K,64] (+bias)(+relu), 4x4 register tile ----
template<int K, bool IN_BF16, bool RELU_IN, bool RELU_OUT, bool BIAS, bool OUT_BF16>
__global__ __launch_bounds__(256) void gemm64x64(
    const void* __restrict__ Xv, const float* __restrict__ W,
    const float* __restrict__ bias, void* __restrict__ Yv, int M)
{
  __shared__ float Wl[K * 64];
  __shared__ float XT[64 * 68];   // [k][row]
  const float* Xf = (const float*)Xv;
  const unsigned short* Xh = (const unsigned short*)Xv;

  for (int i = threadIdx.x; i < K * 16; i += 256)
    reinterpret_cast<float4*>(Wl)[i] = reinterpret_cast<const float4*>(W)[i];

  const int tr = threadIdx.x >> 4;
  const int tc = threadIdx.x & 15;
  const long long rb = (long long)blockIdx.x * 64;

  float acc[4][4] = {};

  for (int ch = 0; ch < K / 64; ++ch) {
    const int c0 = ch * 64;
    __syncthreads();
    for (int f = threadIdx.x; f < 1024; f += 256) {
      int r = f >> 4, k0 = (f & 15) * 4;
      float4 v = make_float4(0.f, 0.f, 0.f, 0.f);
      if (rb + r < M) {
        if (IN_BF16) {
          ushort4 h = *reinterpret_cast<const ushort4*>(Xh + (rb + r) * K + c0 + k0);
          v.x = bf2f(h.x); v.y = bf2f(h.y); v.z = bf2f(h.z); v.w = bf2f(h.w);
        } else {
          v = *reinterpret_cast<const float4*>(Xf + (rb + r) * K + c0 + k0);
        }
        if (RELU_IN) {
          v.x = fmaxf(v.x, 0.f); v.y = fmaxf(v.y, 0.f);
          v.z = fmaxf(v.z, 0.f); v.w = fmaxf(v.w, 0.f);
        }
      }
      XT[(k0 + 0) * 68 + r] = v.x;
      XT[(k0 + 1) * 68 + r] = v.y;
      XT[(k0 + 2) * 68 + r] = v.z;
      XT[(k0 + 3) * 68 + r] = v.w;
    }
    __syncthreads();
    #pragma unroll 8
    for (int k = 0; k < 64; ++k) {
      float4 xa = *reinterpret_cast<const float4*>(&XT[k * 68 + 4 * tr]);
      float4 wb = *reinterpret_cast<const float4*>(&Wl[(c0 + k) * 64 + 4 * tc]);
      acc[0][0] = fmaf(xa.x, wb.x, acc[0][0]); acc[0][1] = fmaf(xa.x, wb.y, acc[0][1]);
      acc[0][2] = fmaf(xa.x, wb.z, acc[0][2]); acc[0][3] = fmaf(xa.x, wb.w, acc[0][3]);
      acc[1][0] = fmaf(xa.y, wb.x, acc[1][0]); acc[1][1] = fmaf(xa.y, wb.y, acc[1][1]);
      acc[1][2] = fmaf(xa.y, wb.z, acc[1][2]); acc[1][3] = fmaf(xa.y, wb.w, acc[1][3]);
      acc[2][0] = fmaf(xa.z, wb.x, acc[2][0]); acc[2][1] = fmaf(xa.z, wb.y, acc[2][1]);
      acc[2][2] = fmaf(xa.z, wb.z, acc[2][2]); acc[2][3] = fmaf(xa.z, wb.w, acc[2][3]);
      acc[3][0] = fmaf(xa.w, wb.x, acc[3][0]); acc[3][1] = fmaf(xa.w, wb.y, acc[3][1]);
      acc[3][2] = fmaf(xa.w, wb.z, acc[3][2]); acc[3][3] = fmaf(xa.w, wb.w, acc[3][3]);
    }
  }

  float4 bb = make_float4(0.f, 0.f, 0.f, 0.f);
  if (BIAS) bb = *reinterpret_cast<const float4*>(bias + 4 * tc);
  #pragma unroll
  for (int rr = 0; rr < 4; ++rr) {
    long long row = rb + 4 * tr + rr;
    if (row < M) {
      float4 o = make_float4(acc[rr][0] + bb.x, acc[rr][1] + bb.y,
                             acc[rr][2] + bb.z, acc[rr][3] + bb.w);
      if (RELU_OUT) {
        o.x = fmaxf(o.x, 0.f); o.y = fmaxf(o.y, 0.f);
        o.z = fmaxf(o.z, 0.f); o.w = fmaxf(o.w, 0.f);
      }
      if (OUT_BF16) {
        ushort4 h; h.x = f2bf(o.x); h.y = f2bf(o.y); h.z = f2bf(o.z); h.w = f2bf(o.w);
        *reinterpret_cast<ushort4*>((unsigned short*)Yv + row * 64 + 4 * tc) = h;
      } else {
        *reinterpret_cast<float4*>((float*)Yv + row * 64 + 4 * tc) = o;
      }
    }
  }
}

// ---- fused pair: P = ( relu( relu(A) @ Wa + ba ) ) @ Wb   (A fp32 -> P bf16) ----
__global__ __launch_bounds__(256) void gemm_dual(
    const float* __restrict__ A, const float* __restrict__ Wa64,
    const float* __restrict__ ba, const float* __restrict__ Wb64,
    unsigned short* __restrict__ P, int M)
{
  __shared__ float Wa[64 * 64];
  __shared__ float Wb[64 * 64];
  __shared__ float XT[64 * 68];
  for (int i = threadIdx.x; i < 1024; i += 256) {
    reinterpret_cast<float4*>(Wa)[i] = reinterpret_cast<const float4*>(Wa64)[i];
    reinterpret_cast<float4*>(Wb)[i] = reinterpret_cast<const float4*>(Wb64)[i];
  }
  const int tr = threadIdx.x >> 4;
  const int tc = threadIdx.x & 15;
  const long long rb = (long long)blockIdx.x * 64;

  // stage relu(A) transposed
  for (int f = threadIdx.x; f < 1024; f += 256) {
    int r = f >> 4, k0 = (f & 15) * 4;
    float4 v = make_float4(0.f, 0.f, 0.f, 0.f);
    if (rb + r < M) {
      v = *reinterpret_cast<const float4*>(A + (rb + r) * 64 + k0);
      v.x = fmaxf(v.x, 0.f); v.y = fmaxf(v.y, 0.f);
      v.z = fmaxf(v.z, 0.f); v.w = fmaxf(v.w, 0.f);
    }
    XT[(k0 + 0) * 68 + r] = v.x;
    XT[(k0 + 1) * 68 + r] = v.y;
    XT[(k0 + 2) * 68 + r] = v.z;
    XT[(k0 + 3) * 68 + r] = v.w;
  }
  __syncthreads();

  float acc[4][4] = {};
  #pragma unroll 8
  for (int k = 0; k < 64; ++k) {
    float4 xa = *reinterpret_cast<const float4*>(&XT[k * 68 + 4 * tr]);
    float4 wb = *reinterpret_cast<const float4*>(&Wa[k * 64 + 4 * tc]);
    acc[0][0] = fmaf(xa.x, wb.x, acc[0][0]); acc[0][1] = fmaf(xa.x, wb.y, acc[0][1]);
    acc[0][2] = fmaf(xa.x, wb.z, acc[0][2]); acc[0][3] = fmaf(xa.x, wb.w, acc[0][3]);
    acc[1][0] = fmaf(xa.y, wb.x, acc[1][0]); acc[1][1] = fmaf(xa.y, wb.y, acc[1][1]);
    acc[1][2] = fmaf(xa.y, wb.z, acc[1][2]); acc[1][3] = fmaf(xa.y, wb.w, acc[1][3]);
    acc[2][0] = fmaf(xa.z, wb.x, acc[2][0]); acc[2][1] = fmaf(xa.z, wb.y, acc[2][1]);
    acc[2][2] = fmaf(xa.z, wb.z, acc[2][2]); acc[2][3] = fmaf(xa.z, wb.w, acc[2][3]);
    acc[3][0] = fmaf(xa.w, wb.x, acc[3][0]); acc[3][1] = fmaf(xa.w, wb.y, acc[3][1]);
    acc[3][2] = fmaf(xa.w, wb.z, acc[3][2]); acc[3][3] = fmaf(xa.w, wb.w, acc[3][3]);
  }
  // h = relu(acc + ba); write back transposed into XT (4 x ds_write_b128 per thread)
  float4 bb = *reinterpret_cast<const float4*>(ba + 4 * tc);
  float h[4][4];
  #pragma unroll
  for (int rr = 0; rr < 4; ++rr) {
    h[rr][0] = fmaxf(acc[rr][0] + bb.x, 0.f);
    h[rr][1] = fmaxf(acc[rr][1] + bb.y, 0.f);
    h[rr][2] = fmaxf(acc[rr][2] + bb.z, 0.f);
    h[rr][3] = fmaxf(acc[rr][3] + bb.w, 0.f);
  }
  __syncthreads();   // all reads of XT done
  #pragma unroll
  for (int cc = 0; cc < 4; ++cc) {
    float4 v = make_float4(h[0][cc], h[1][cc], h[2][cc], h[3][cc]);
    *reinterpret_cast<float4*>(&XT[(4 * tc + cc) * 68 + 4 * tr]) = v;
  }
  __syncthreads();

  float ac2[4][4] = {};
  #pragma unroll 8
  for (int k = 0; k < 64; ++k) {
    float4 xa = *reinterpret_cast<const float4*>(&XT[k * 68 + 4 * tr]);
    float4 wb = *reinterpret_cast<const float4*>(&Wb[k * 64 + 4 * tc]);
    ac2[0][0] = fmaf(xa.x, wb.x, ac2[0][0]); ac2[0][1] = fmaf(xa.x, wb.y, ac2[0][1]);
    ac2[0][2] = fmaf(xa.x, wb.z, ac2[0][2]); ac2[0][3] = fmaf(xa.x, wb.w, ac2[0][3]);
    ac2[1][0] = fmaf(xa.y, wb.x, ac2[1][0]); ac2[1][1] = fmaf(xa.y, wb.y, ac2[1][1]);
    ac2[1][2] = fmaf(xa.y, wb.z, ac2[1][2]); ac2[1][3] = fmaf(xa.y, wb.w, ac2[1][3]);
    ac2[2][0] = fmaf(xa.z, wb.x, ac2[2][0]); ac2[2][1] = fmaf(xa.z, wb.y, ac2[2][1]);
    ac2[2][2] = fmaf(xa.z, wb.z, ac2[2][2]); ac2[2][3] = fmaf(xa.z, wb.w, ac2[2][3]);
    ac2[3][0] = fmaf(xa.w, wb.x, ac2[3][0]); ac2[3][1] = fmaf(xa.w, wb.y, ac2[3][1]);
    ac2[3][2] = fmaf(xa.w, wb.z, ac2[3][2]); ac2[3][3] = fmaf(xa.w, wb.w, ac2[3][3]);
  }
  #pragma unroll
  for (int rr = 0; rr < 4; ++rr) {
    long long row = rb + 4 * tr + rr;
    if (row < M) {
      ushort4 hh;
      hh.x = f2bf(ac2[rr][0]); hh.y = f2bf(ac2[rr][1]);
      hh.z = f2bf(ac2[rr][2]); hh.w = f2bf(ac2[rr][3]);
      *reinterpret_cast<ushort4*>(P + row * 64 + 4 * tc) = hh;
    }
  }
}

// ---------------- partition pass 1: per-block bucket histogram ----------------
__global__ __launch_bounds__(256) void part_hist(
    const int* __restrict__ dst, int* __restrict__ blockHist,
    int E, int NB, int nblocksB)
{
  __shared__ int hist[MAXNB];
  for (int i = threadIdx.x; i < NB; i += 256) hist[i] = 0;
  __syncthreads();
  int base = blockIdx.x * EB_CHUNK;
  int end = min(base + EB_CHUNK, E);
  for (int e = base + threadIdx.x; e < end; e += 256)
    atomicAdd(&hist[dst[e] >> 8], 1);
  __syncthreads();
  for (int i = threadIdx.x; i < NB; i += 256)
    blockHist[(long long)i * nblocksB + blockIdx.x] = hist[i];
}

// ---------------- scan blockHist within each bucket ----------------
__global__ __launch_bounds__(256) void scan_bucket_blocks(
    int* __restrict__ blockHist, int* __restrict__ bucketTotal, int nblocksB)
{
  int* row = blockHist + (long long)blockIdx.x * nblocksB;
  __shared__ int tsum[256];
  int v[4]; int local = 0;
  int i0 = threadIdx.x * 4;
  #pragma unroll
  for (int k = 0; k < 4; ++k) { int g = i0 + k; v[k] = (g < nblocksB) ? row[g] : 0; local += v[k]; }
  tsum[threadIdx.x] = local;
  __syncthreads();
  for (int off = 1; off < 256; off <<= 1) {
    int y = (threadIdx.x >= off) ? tsum[threadIdx.x - off] : 0;
    __syncthreads();
    tsum[threadIdx.x] += y;
    __syncthreads();
  }
  int pref = tsum[threadIdx.x] - local;
  #pragma unroll
  for (int k = 0; k < 4; ++k) { int g = i0 + k; if (g < nblocksB) { row[g] = pref; pref += v[k]; } }
  if (threadIdx.x == 255) bucketTotal[blockIdx.x] = tsum[255];
}

// ---------------- exclusive scan of bucket totals ----------------
__global__ __launch_bounds__(512) void scan_buckets(
    const int* __restrict__ bucketTotal, int* __restrict__ bucketBase, int NB)
{
  __shared__ int tsum[512];
  int t = threadIdx.x;
  int v = (t < NB) ? bucketTotal[t] : 0;
  tsum[t] = v;
  __syncthreads();
  for (int off = 1; off < 512; off <<= 1) {
    int y = (t >= off) ? tsum[t - off] : 0;
    __syncthreads();
    tsum[t] += y;
    __syncthreads();
  }
  if (t < NB) bucketBase[t] = tsum[t] - v;
  if (t == NB - 1) bucketBase[NB] = tsum[t];
}

// ---------------- partition pass 2: scatter packed (src | localDst<<24) ----------------
__global__ __launch_bounds__(256) void part_scatter(
    const int* __restrict__ src, const int* __restrict__ dst,
    const int* __restrict__ blockHist, const int* __restrict__ bucketBase,
    unsigned* __restrict__ ebuf, int E, int NB, int nblocksB)
{
  __shared__ int cursor[MAXNB];
  for (int i = threadIdx.x; i < NB; i += 256)
    cursor[i] = bucketBase[i] + blockHist[(long long)i * nblocksB + blockIdx.x];
  __syncthreads();
  int base = blockIdx.x * EB_CHUNK;
  int end = min(base + EB_CHUNK, E);
  for (int e = base + threadIdx.x; e < end; e += 256) {
    int s = src[e], d = dst[e];
    int p = atomicAdd(&cursor[d >> 8], 1);
    ebuf[p] = (unsigned)s | ((unsigned)(d & (NPB - 1)) << 24);
  }
}

// ---------------- per-bucket counting sort -> rowptr + col ----------------
__global__ __launch_bounds__(256) void bucket_csr(
    const unsigned* __restrict__ ebuf, const int* __restrict__ bucketBase,
    int* __restrict__ rowptr, int* __restrict__ col, int N, int NB)
{
  int b = blockIdx.x;
  int eb = bucketBase[b], ee = bucketBase[b + 1];
  int nodeBase = b * NPB;
  __shared__ int hist[NPB];
  __shared__ int tsum[NPB];
  __shared__ int cur[NPB];
  hist[threadIdx.x] = 0;
  __syncthreads();
  for (int e = eb + threadIdx.x; e < ee; e += 256)
    atomicAdd(&hist[ebuf[e] >> 24], 1);
  __syncthreads();
  int local = hist[threadIdx.x];
  tsum[threadIdx.x] = local;
  __syncthreads();
  for (int off = 1; off < 256; off <<= 1) {
    int y = (threadIdx.x >= off) ? tsum[threadIdx.x - off] : 0;
    __syncthreads();
    tsum[threadIdx.x] += y;
    __syncthreads();
  }
  int pref = tsum[threadIdx.x] - local;
  int node = nodeBase + threadIdx.x;
  if (node < N) rowptr[node] = eb + pref;
  if (b == NB - 1 && threadIdx.x == 0) rowptr[N] = ee;
  cur[threadIdx.x] = pref;
  __syncthreads();
  for (int e = eb + threadIdx.x; e < ee; e += 256) {
    unsigned w = ebuf[e];
    int l = (int)(w >> 24);
    int p = eb + atomicAdd(&cur[l], 1);
    col[p] = (int)(w & 0xFFFFFFu);
  }
}

// ---- GIN aggregate (bf16 gather) + fused BN stats ----
__global__ __launch_bounds__(256) void gin_gather_bf16(
    const int* __restrict__ rowptr, const int* __restrict__ col,
    const unsigned short* __restrict__ P, const float* __restrict__ b1,
    float* __restrict__ A, float* __restrict__ stats, int N, int nodeStride)
{
  const int lane = threadIdx.x & 63;
  const int wv = threadIdx.x >> 6;
  const int half = lane >> 5;        // 0: even edges + self, 1: odd edges
  const int cl = lane & 31;          // cols 2cl, 2cl+1
  float s0 = 0.f, q0 = 0.f, s1 = 0.f, q1 = 0.f;

  for (int node = blockIdx.x * 4 + wv; node < N; node += nodeStride) {
    int beg = rowptr[node], end = rowptr[node + 1];
    float a0, a1;
    if (half == 0) {
      ushort2 h = *reinterpret_cast<const ushort2*>(P + (long long)node * 64 + 2 * cl);
      a0 = bf2f(h.x) + b1[2 * cl];
      a1 = bf2f(h.y) + b1[2 * cl + 1];
    } else { a0 = 0.f; a1 = 0.f; }
    int j = beg + half;
    for (; j + 6 < end; j += 8) {     // 4 edges in flight per half
      int sA = col[j], sB = col[j + 2], sC = col[j + 4], sD = col[j + 6];
      ushort2 hA = *reinterpret_cast<const ushort2*>(P + (long long)sA * 64 + 2 * cl);
      ushort2 hB = *reinterpret_cast<const ushort2*>(P + (long long)sB * 64 + 2 * cl);
      ushort2 hC = *reinterpret_cast<const ushort2*>(P + (long long)sC * 64 + 2 * cl);
      ushort2 hD = *reinterpret_cast<const ushort2*>(P + (long long)sD * 64 + 2 * cl);
      a0 += bf2f(hA.x); a1 += bf2f(hA.y);
      a0 += bf2f(hB.x); a1 += bf2f(hB.y);
      a0 += bf2f(hC.x); a1 += bf2f(hC.y);
      a0 += bf2f(hD.x); a1 += bf2f(hD.y);
    }
    for (; j + 2 < end; j += 4) {
      int sA = col[j], sB = col[j + 2];
      ushort2 hA = *reinterpret_cast<const ushort2*>(P + (long long)sA * 64 + 2 * cl);
      ushort2 hB = *reinterpret_cast<const ushort2*>(P + (long long)sB * 64 + 2 * cl);
      a0 += bf2f(hA.x); a1 += bf2f(hA.y);
      a0 += bf2f(hB.x); a1 += bf2f(hB.y);
    }
    if (j < end) {
      int sA = col[j];
      ushort2 hA = *reinterpret_cast<const ushort2*>(P + (long long)sA * 64 + 2 * cl);
      a0 += bf2f(hA.x); a1 += bf2f(hA.y);
    }
    a0 += __shfl_xor(a0, 32);
    a1 += __shfl_xor(a1, 32);
    if (half == 0) {
      *reinterpret_cast<float2*>(A + (long long)node * 64 + 2 * cl) = make_float2(a0, a1);
      float r0 = fmaxf(a0, 0.f), r1 = fmaxf(a1, 0.f);
      s0 += r0; q0 += r0 * r0; s1 += r1; q1 += r1 * r1;
    }
  }

  __shared__ float st[4][4][32];
  if (half == 0) {
    st[wv][0][cl] = s0; st[wv][1][cl] = q0; st[wv][2][cl] = s1; st[wv][3][cl] = q1;
  }
  __syncthreads();
  if (threadIdx.x < 64) {
    int c = threadIdx.x;
    int cl2 = c >> 1, p = c & 1;
    int is = p ? 2 : 0, iq = p ? 3 : 1;
    float s = st[0][is][cl2] + st[1][is][cl2] + st[2][is][cl2] + st[3][is][cl2];
    float q = st[0][iq][cl2] + st[1][iq][cl2] + st[2][iq][cl2] + st[3][iq][cl2];
    atomicAdd(&stats[c], s);
    atomicAdd(&stats[64 + c], q);
  }
}

// ---------------- fold BN into W2/b2 ----------------
__global__ void bn_fold(
    const float* __restrict__ stats, const float* __restrict__ g, const float* __restrict__ be,
    const float* __restrict__ W2, const float* __restrict__ b2,
    float* __restrict__ W2f, float* __restrict__ b2f, float invN)
{
  int j = threadIdx.x;
  __shared__ float sc[64], sh[64];
  float mu = stats[j] * invN;
  float var = stats[64 + j] * invN - mu * mu;
  float s = g[j] * rsqrtf(var + 1e-5f);
  sc[j] = s;
  sh[j] = be[j] - mu * s;
  __syncthreads();
  float acc = b2[j];
  for (int k = 0; k < 64; ++k) {
    float w = W2[k * 64 + j];
    W2f[k * 64 + j] = sc[k] * w;
    acc += sh[k] * w;
  }
  b2f[j] = acc;
}

// ---------------- global add pool over sorted batch ----------------
__global__ __launch_bounds__(256) void pool_sorted(
    const float* __restrict__ Hf, const int* __restrict__ batch,
    float* __restrict__ out, int N, int G)
{
  int g = blockIdx.x * 4 + (threadIdx.x >> 6);
  int c = threadIdx.x & 63;
  if (g >= G) return;
  int lo = 0, hi = N;
  while (lo < hi) { int mid = (lo + hi) >> 1; if (batch[mid] < g) lo = mid + 1; else hi = mid; }
  int beg = lo;
  hi = N;
  while (lo < hi) { int mid = (lo + hi) >> 1; if (batch[mid] < g + 1) lo = mid + 1; else hi = mid; }
  int end = lo;
  float acc = 0.f;
  for (int r = beg; r < end; ++r) acc += Hf[(long long)r * 64 + c];
  out[(long long)g * 64 + c] = acc;
}

extern "C" void kernel_launch(void* const* d_in, const int* in_sizes, int n_in,
                              void* d_out, int out_size, void* d_ws, size_t ws_size,
                              hipStream_t stream) {
  const float* x      = (const float*)d_in[0];
  const int*   ei     = (const int*)d_in[1];
  const int*   batch  = (const int*)d_in[2];
  const float* W1_0 = (const float*)d_in[3];
  const float* b1_0 = (const float*)d_in[4];
  const float* g_0  = (const float*)d_in[5];
  const float* be_0 = (const float*)d_in[6];
  const float* W2_0 = (const float*)d_in[7];
  const float* b2_0 = (const float*)d_in[8];
  const float* W1_1 = (const float*)d_in[9];
  const float* b1_1 = (const float*)d_in[10];
  const float* g_1  = (const float*)d_in[11];
  const float* be_1 = (const float*)d_in[12];
  const float* W2_1 = (const float*)d_in[13];
  const float* b2_1 = (const float*)d_in[14];

  const int N = in_sizes[0] / 128;
  const int E = in_sizes[1] / 2;
  const int G = (out_size - N * 64) / 64;
  const int* srcI = ei;
  const int* dstI = ei + E;

  float* outG = (float*)d_out;                       // [G,64]
  float* outH = (float*)d_out + (long long)G * 64;   // [N,64] fp32 (doubles as A buffer)

  const int NB = cdiv_ll(N, NPB);
  const int nblocksB = cdiv_ll(E, EB_CHUNK);

  // ---- workspace layout ----
  char* w = (char*)d_ws;
  size_t r2 = (size_t)E * 4;
  if ((size_t)N * 64 * 2 > r2) r2 = (size_t)N * 64 * 2;
  unsigned* ebuf        = (unsigned*)w;              // CSR-build only
  unsigned short* Pbuf  = (unsigned short*)w;        // bf16 P table (aliases ebuf)
  w += r2;
  int* col       = (int*)w; w += (size_t)E * 4;
  int* rowptr    = (int*)w; w += (size_t)(N + 1) * 4;
  int* blockHist = (int*)w; w += (size_t)NB * nblocksB * 4;
  int* bucketTotal = (int*)w; w += (size_t)NB * 4;
  int* bucketBase  = (int*)w; w += (size_t)(NB + 1) * 4;
  float* stats0 = (float*)w; w += 128 * 4;
  float* stats1 = (float*)w; w += 128 * 4;
  float* W2f0   = (float*)w; w += 64 * 64 * 4;
  float* b2f0   = (float*)w; w += 64 * 4;
  float* W2f1   = (float*)w; w += 64 * 64 * 4;
  float* b2f1   = (float*)w; w += 64 * 4;

  const int gemmGrid = cdiv_ll(N, 64);
  const int gatherGrid = 2048;                       // 8 blocks/CU -> full wave slots

  hipMemsetAsync(stats0, 0, 256 * sizeof(float), stream);

  // ---- CSR build ----
  part_hist<<<nblocksB, 256, 0, stream>>>(dstI, blockHist, E, NB, nblocksB);
  scan_bucket_blocks<<<NB, 256, 0, stream>>>(blockHist, bucketTotal, nblocksB);
  scan_buckets<<<1, 512, 0, stream>>>(bucketTotal, bucketBase, NB);
  part_scatter<<<nblocksB, 256, 0, stream>>>(srcI, dstI, blockHist, bucketBase, ebuf, E, NB, nblocksB);
  bucket_csr<<<NB, 256, 0, stream>>>(ebuf, bucketBase, rowptr, col, N, NB);

  // ---- layer 0 ----
  gemm64x64<128, false, false, false, false, true><<<gemmGrid, 256, 0, stream>>>(x, W1_0, nullptr, Pbuf, N);
  gin_gather_bf16<<<gatherGrid, 256, 0, stream>>>(rowptr, col, Pbuf, b1_0, outH, stats0, N, gatherGrid * 4);
  bn_fold<<<1, 64, 0, stream>>>(stats0, g_0, be_0, W2_0, b2_0, W2f0, b2f0, 1.0f / N);
  // h1 = relu(relu(A0)@W2f0+b2f0); P1 = h1@W1_1 -> bf16 (fused, Pbuf in-place ok: tile-local)
  gemm_dual<<<gemmGrid, 256, 0, stream>>>(outH, W2f0, b2f0, W1_1, Pbuf, N);

  // ---- layer 1 ----
  gin_gather_bf16<<<gatherGrid, 256, 0, stream>>>(rowptr, col, Pbuf, b1_1, outH, stats1, N, gatherGrid * 4);
  bn_fold<<<1, 64, 0, stream>>>(stats1, g_1, be_1, W2_1, b2_1, W2f1, b2f1, 1.0f / N);
  // h2 = relu(relu(A1)@W2f1+b2f1) -> fp32 in-place in outH
  gemm64x64<64, false, true, true, true, false><<<gemmGrid, 256, 0, stream>>>(outH, W2f1, b2f1, outH, N);

  // ---- global add pool ----
  pool_sorted<<<cdiv_ll(G, 4), 256, 0, stream>>>(outH, batch, outG, N, G);
}

// Round 6
// 440.027 us; speedup vs baseline: 13.2026x; 1.0129x over previous
//
#include <hip/hip_runtime.h>

static inline int cdiv_ll(long long a, long long b){ return (int)((a + b - 1) / b); }

#define EB_CHUNK 8192   // edges per partition block
#define NPB 256         // nodes per bucket (pow2: bucket = dst >> 8)
#define MAXNB 512       // max buckets supported in LDS

__device__ __forceinline__ float bf2f(unsigned short h) {
  unsigned u = (unsigned)h << 16;
  return __uint_as_float(u);
}
__device__ __forceinline__ unsigned short f2bf(float f) {
  unsigned u = __float_as_uint(f);
  u += 0x7FFF + ((u >> 16) & 1);   // round-to-nearest-even
  return (unsigned short)(u >> 16);
}

// ---------------- GEMM: Y[M,64] = op(X[M,K]) @ W[K,64] (+bias)(+relu), 4x4 register tile ----
template<int K, bool IN_BF16, bool RELU_IN, bool RELU_OUT, bool BIAS, bool OUT_BF16>
__global__ __launch_bounds__(256) void gemm64x64(
    const void* __restrict__ Xv, const float* __restrict__ W,
    const float* __restrict__ bias, void* __restrict__ Yv, int M)
{
  __shared__ float Wl[K * 64];
  __shared__ float XT[64 * 68];   // [k][row]
  const float* Xf = (const float*)Xv;
  const unsigned short* Xh = (const unsigned short*)Xv;

  for (int i = threadIdx.x; i < K * 16; i += 256)
    reinterpret_cast<float4*>(Wl)[i] = reinterpret_cast<const float4*>(W)[i];

  const int tr = threadIdx.x >> 4;
  const int tc = threadIdx.x & 15;
  const long long rb = (long long)blockIdx.x * 64;

  float acc[4][4] = {};

  for (int ch = 0; ch < K / 64; ++ch) {
    const int c0 = ch * 64;
    __syncthreads();
    for (int f = threadIdx.x; f < 1024; f += 256) {
      int r = f >> 4, k0 = (f & 15) * 4;
      float4 v = make_float4(0.f, 0.f, 0.f, 0.f);
      if (rb + r < M) {
        if (IN_BF16) {
          ushort4 h = *reinterpret_cast<const ushort4*>(Xh + (rb + r) * K + c0 + k0);
          v.x = bf2f(h.x); v.y = bf2f(h.y); v.z = bf2f(h.z); v.w = bf2f(h.w);
        } else {
          v = *reinterpret_cast<const float4*>(Xf + (rb + r) * K + c0 + k0);
        }
        if (RELU_IN) {
          v.x = fmaxf(v.x, 0.f); v.y = fmaxf(v.y, 0.f);
          v.z = fmaxf(v.z, 0.f); v.w = fmaxf(v.w, 0.f);
        }
      }
      XT[(k0 + 0) * 68 + r] = v.x;
      XT[(k0 + 1) * 68 + r] = v.y;
      XT[(k0 + 2) * 68 + r] = v.z;
      XT[(k0 + 3) * 68 + r] = v.w;
    }
    __syncthreads();
    #pragma unroll 8
    for (int k = 0; k < 64; ++k) {
      float4 xa = *reinterpret_cast<const float4*>(&XT[k * 68 + 4 * tr]);
      float4 wb = *reinterpret_cast<const float4*>(&Wl[(c0 + k) * 64 + 4 * tc]);
      acc[0][0] = fmaf(xa.x, wb.x, acc[0][0]); acc[0][1] = fmaf(xa.x, wb.y, acc[0][1]);
      acc[0][2] = fmaf(xa.x, wb.z, acc[0][2]); acc[0][3] = fmaf(xa.x, wb.w, acc[0][3]);
      acc[1][0] = fmaf(xa.y, wb.x, acc[1][0]); acc[1][1] = fmaf(xa.y, wb.y, acc[1][1]);
      acc[1][2] = fmaf(xa.y, wb.z, acc[1][2]); acc[1][3] = fmaf(xa.y, wb.w, acc[1][3]);
      acc[2][0] = fmaf(xa.z, wb.x, acc[2][0]); acc[2][1] = fmaf(xa.z, wb.y, acc[2][1]);
      acc[2][2] = fmaf(xa.z, wb.z, acc[2][2]); acc[2][3] = fmaf(xa.z, wb.w, acc[2][3]);
      acc[3][0] = fmaf(xa.w, wb.x, acc[3][0]); acc[3][1] = fmaf(xa.w, wb.y, acc[3][1]);
      acc[3][2] = fmaf(xa.w, wb.z, acc[3][2]); acc[3][3] = fmaf(xa.w, wb.w, acc[3][3]);
    }
  }

  float4 bb = make_float4(0.f, 0.f, 0.f, 0.f);
  if (BIAS) bb = *reinterpret_cast<const float4*>(bias + 4 * tc);
  #pragma unroll
  for (int rr = 0; rr < 4; ++rr) {
    long long row = rb + 4 * tr + rr;
    if (row < M) {
      float4 o = make_float4(acc[rr][0] + bb.x, acc[rr][1] + bb.y,
                             acc[rr][2] + bb.z, acc[rr][3] + bb.w);
      if (RELU_OUT) {
        o.x = fmaxf(o.x, 0.f); o.y = fmaxf(o.y, 0.f);
        o.z = fmaxf(o.z, 0.f); o.w = fmaxf(o.w, 0.f);
      }
      if (OUT_BF16) {
        ushort4 h; h.x = f2bf(o.x); h.y = f2bf(o.y); h.z = f2bf(o.z); h.w = f2bf(o.w);
        *reinterpret_cast<ushort4*>((unsigned short*)Yv + row * 64 + 4 * tc) = h;
      } else {
        *reinterpret_cast<float4*>((float*)Yv + row * 64 + 4 * tc) = o;
      }
    }
  }
}

// ---- fused pair: P = ( relu( relu(A) @ Wa + ba ) ) @ Wb   (A fp32 -> P bf16) ----
__global__ __launch_bounds__(256) void gemm_dual(
    const float* __restrict__ A, const float* __restrict__ Wa64,
    const float* __restrict__ ba, const float* __restrict__ Wb64,
    unsigned short* __restrict__ P, int M)
{
  __shared__ float Wa[64 * 64];
  __shared__ float Wb[64 * 64];
  __shared__ float XT[64 * 68];
  for (int i = threadIdx.x; i < 1024; i += 256) {
    reinterpret_cast<float4*>(Wa)[i] = reinterpret_cast<const float4*>(Wa64)[i];
    reinterpret_cast<float4*>(Wb)[i] = reinterpret_cast<const float4*>(Wb64)[i];
  }
  const int tr = threadIdx.x >> 4;
  const int tc = threadIdx.x & 15;
  const long long rb = (long long)blockIdx.x * 64;

  for (int f = threadIdx.x; f < 1024; f += 256) {
    int r = f >> 4, k0 = (f & 15) * 4;
    float4 v = make_float4(0.f, 0.f, 0.f, 0.f);
    if (rb + r < M) {
      v = *reinterpret_cast<const float4*>(A + (rb + r) * 64 + k0);
      v.x = fmaxf(v.x, 0.f); v.y = fmaxf(v.y, 0.f);
      v.z = fmaxf(v.z, 0.f); v.w = fmaxf(v.w, 0.f);
    }
    XT[(k0 + 0) * 68 + r] = v.x;
    XT[(k0 + 1) * 68 + r] = v.y;
    XT[(k0 + 2) * 68 + r] = v.z;
    XT[(k0 + 3) * 68 + r] = v.w;
  }
  __syncthreads();

  float acc[4][4] = {};
  #pragma unroll 8
  for (int k = 0; k < 64; ++k) {
    float4 xa = *reinterpret_cast<const float4*>(&XT[k * 68 + 4 * tr]);
    float4 wb = *reinterpret_cast<const float4*>(&Wa[k * 64 + 4 * tc]);
    acc[0][0] = fmaf(xa.x, wb.x, acc[0][0]); acc[0][1] = fmaf(xa.x, wb.y, acc[0][1]);
    acc[0][2] = fmaf(xa.x, wb.z, acc[0][2]); acc[0][3] = fmaf(xa.x, wb.w, acc[0][3]);
    acc[1][0] = fmaf(xa.y, wb.x, acc[1][0]); acc[1][1] = fmaf(xa.y, wb.y, acc[1][1]);
    acc[1][2] = fmaf(xa.y, wb.z, acc[1][2]); acc[1][3] = fmaf(xa.y, wb.w, acc[1][3]);
    acc[2][0] = fmaf(xa.z, wb.x, acc[2][0]); acc[2][1] = fmaf(xa.z, wb.y, acc[2][1]);
    acc[2][2] = fmaf(xa.z, wb.z, acc[2][2]); acc[2][3] = fmaf(xa.z, wb.w, acc[2][3]);
    acc[3][0] = fmaf(xa.w, wb.x, acc[3][0]); acc[3][1] = fmaf(xa.w, wb.y, acc[3][1]);
    acc[3][2] = fmaf(xa.w, wb.z, acc[3][2]); acc[3][3] = fmaf(xa.w, wb.w, acc[3][3]);
  }
  float4 bb = *reinterpret_cast<const float4*>(ba + 4 * tc);
  float h[4][4];
  #pragma unroll
  for (int rr = 0; rr < 4; ++rr) {
    h[rr][0] = fmaxf(acc[rr][0] + bb.x, 0.f);
    h[rr][1] = fmaxf(acc[rr][1] + bb.y, 0.f);
    h[rr][2] = fmaxf(acc[rr][2] + bb.z, 0.f);
    h[rr][3] = fmaxf(acc[rr][3] + bb.w, 0.f);
  }
  __syncthreads();
  #pragma unroll
  for (int cc = 0; cc < 4; ++cc) {
    float4 v = make_float4(h[0][cc], h[1][cc], h[2][cc], h[3][cc]);
    *reinterpret_cast<float4*>(&XT[(4 * tc + cc) * 68 + 4 * tr]) = v;
  }
  __syncthreads();

  float ac2[4][4] = {};
  #pragma unroll 8
  for (int k = 0; k < 64; ++k) {
    float4 xa = *reinterpret_cast<const float4*>(&XT[k * 68 + 4 * tr]);
    float4 wb = *reinterpret_cast<const float4*>(&Wb[k * 64 + 4 * tc]);
    ac2[0][0] = fmaf(xa.x, wb.x, ac2[0][0]); ac2[0][1] = fmaf(xa.x, wb.y, ac2[0][1]);
    ac2[0][2] = fmaf(xa.x, wb.z, ac2[0][2]); ac2[0][3] = fmaf(xa.x, wb.w, ac2[0][3]);
    ac2[1][0] = fmaf(xa.y, wb.x, ac2[1][0]); ac2[1][1] = fmaf(xa.y, wb.y, ac2[1][1]);
    ac2[1][2] = fmaf(xa.y, wb.z, ac2[1][2]); ac2[1][3] = fmaf(xa.y, wb.w, ac2[1][3]);
    ac2[2][0] = fmaf(xa.z, wb.x, ac2[2][0]); ac2[2][1] = fmaf(xa.z, wb.y, ac2[2][1]);
    ac2[2][2] = fmaf(xa.z, wb.z, ac2[2][2]); ac2[2][3] = fmaf(xa.z, wb.w, ac2[2][3]);
    ac2[3][0] = fmaf(xa.w, wb.x, ac2[3][0]); ac2[3][1] = fmaf(xa.w, wb.y, ac2[3][1]);
    ac2[3][2] = fmaf(xa.w, wb.z, ac2[3][2]); ac2[3][3] = fmaf(xa.w, wb.w, ac2[3][3]);
  }
  #pragma unroll
  for (int rr = 0; rr < 4; ++rr) {
    long long row = rb + 4 * tr + rr;
    if (row < M) {
      ushort4 hh;
      hh.x = f2bf(ac2[rr][0]); hh.y = f2bf(ac2[rr][1]);
      hh.z = f2bf(ac2[rr][2]); hh.w = f2bf(ac2[rr][3]);
      *reinterpret_cast<ushort4*>(P + row * 64 + 4 * tc) = hh;
    }
  }
}

// ---------------- partition pass 1: per-block bucket histogram ----------------
__global__ __launch_bounds__(256) void part_hist(
    const int* __restrict__ dst, int* __restrict__ blockHist,
    int E, int NB, int nblocksB)
{
  __shared__ int hist[MAXNB];
  for (int i = threadIdx.x; i < NB; i += 256) hist[i] = 0;
  __syncthreads();
  int base = blockIdx.x * EB_CHUNK;
  int end = min(base + EB_CHUNK, E);
  for (int e = base + threadIdx.x; e < end; e += 256)
    atomicAdd(&hist[dst[e] >> 8], 1);
  __syncthreads();
  for (int i = threadIdx.x; i < NB; i += 256)
    blockHist[(long long)i * nblocksB + blockIdx.x] = hist[i];
}

// ---------------- scan blockHist within each bucket ----------------
__global__ __launch_bounds__(256) void scan_bucket_blocks(
    int* __restrict__ blockHist, int* __restrict__ bucketTotal, int nblocksB)
{
  int* row = blockHist + (long long)blockIdx.x * nblocksB;
  __shared__ int tsum[256];
  int v[4]; int local = 0;
  int i0 = threadIdx.x * 4;
  #pragma unroll
  for (int k = 0; k < 4; ++k) { int g = i0 + k; v[k] = (g < nblocksB) ? row[g] : 0; local += v[k]; }
  tsum[threadIdx.x] = local;
  __syncthreads();
  for (int off = 1; off < 256; off <<= 1) {
    int y = (threadIdx.x >= off) ? tsum[threadIdx.x - off] : 0;
    __syncthreads();
    tsum[threadIdx.x] += y;
    __syncthreads();
  }
  int pref = tsum[threadIdx.x] - local;
  #pragma unroll
  for (int k = 0; k < 4; ++k) { int g = i0 + k; if (g < nblocksB) { row[g] = pref; pref += v[k]; } }
  if (threadIdx.x == 255) bucketTotal[blockIdx.x] = tsum[255];
}

// ---------------- exclusive scan of bucket totals ----------------
__global__ __launch_bounds__(512) void scan_buckets(
    const int* __restrict__ bucketTotal, int* __restrict__ bucketBase, int NB)
{
  __shared__ int tsum[512];
  int t = threadIdx.x;
  int v = (t < NB) ? bucketTotal[t] : 0;
  tsum[t] = v;
  __syncthreads();
  for (int off = 1; off < 512; off <<= 1) {
    int y = (t >= off) ? tsum[t - off] : 0;
    __syncthreads();
    tsum[t] += y;
    __syncthreads();
  }
  if (t < NB) bucketBase[t] = tsum[t] - v;
  if (t == NB - 1) bucketBase[NB] = tsum[t];
}

// ---------------- partition pass 2: scatter packed (src | localDst<<24) ----------------
__global__ __launch_bounds__(256) void part_scatter(
    const int* __restrict__ src, const int* __restrict__ dst,
    const int* __restrict__ blockHist, const int* __restrict__ bucketBase,
    unsigned* __restrict__ ebuf, int E, int NB, int nblocksB)
{
  __shared__ int cursor[MAXNB];
  for (int i = threadIdx.x; i < NB; i += 256)
    cursor[i] = bucketBase[i] + blockHist[(long long)i * nblocksB + blockIdx.x];
  __syncthreads();
  int base = blockIdx.x * EB_CHUNK;
  int end = min(base + EB_CHUNK, E);
  for (int e = base + threadIdx.x; e < end; e += 256) {
    int s = src[e], d = dst[e];
    int p = atomicAdd(&cursor[d >> 8], 1);
    ebuf[p] = (unsigned)s | ((unsigned)(d & (NPB - 1)) << 24);
  }
}

// ---------------- per-bucket counting sort -> rowptr + col ----------------
__global__ __launch_bounds__(256) void bucket_csr(
    const unsigned* __restrict__ ebuf, const int* __restrict__ bucketBase,
    int* __restrict__ rowptr, int* __restrict__ col, int N, int NB)
{
  int b = blockIdx.x;
  int eb = bucketBase[b], ee = bucketBase[b + 1];
  int nodeBase = b * NPB;
  __shared__ int hist[NPB];
  __shared__ int tsum[NPB];
  __shared__ int cur[NPB];
  hist[threadIdx.x] = 0;
  __syncthreads();
  for (int e = eb + threadIdx.x; e < ee; e += 256)
    atomicAdd(&hist[ebuf[e] >> 24], 1);
  __syncthreads();
  int local = hist[threadIdx.x];
  tsum[threadIdx.x] = local;
  __syncthreads();
  for (int off = 1; off < 256; off <<= 1) {
    int y = (threadIdx.x >= off) ? tsum[threadIdx.x - off] : 0;
    __syncthreads();
    tsum[threadIdx.x] += y;
    __syncthreads();
  }
  int pref = tsum[threadIdx.x] - local;
  int node = nodeBase + threadIdx.x;
  if (node < N) rowptr[node] = eb + pref;
  if (b == NB - 1 && threadIdx.x == 0) rowptr[N] = ee;
  cur[threadIdx.x] = pref;
  __syncthreads();
  for (int e = eb + threadIdx.x; e < ee; e += 256) {
    unsigned w = ebuf[e];
    int l = (int)(w >> 24);
    int p = eb + atomicAdd(&cur[l], 1);
    col[p] = (int)(w & 0xFFFFFFu);
  }
}

// ---- GIN aggregate: quarter-wave rows (ushort4/lane, 16 lanes/row, 4 edges in flight) ----
//      A[i] = b1 + P[i] + sum_{j->i} P[j];  stats += {relu(A), relu(A)^2}
__global__ __launch_bounds__(256) void gin_gather_bf16(
    const int* __restrict__ rowptr, const int* __restrict__ col,
    const unsigned short* __restrict__ P, const float* __restrict__ b1,
    float* __restrict__ A, float* __restrict__ stats, int N, int nodeStride)
{
  const int lane = threadIdx.x & 63;
  const int wv = threadIdx.x >> 6;
  const int q = lane >> 4;          // quarter 0..3 (edge interleave)
  const int cl = lane & 15;         // col group: cols 4cl..4cl+3
  float s[4] = {0.f, 0.f, 0.f, 0.f};
  float sq[4] = {0.f, 0.f, 0.f, 0.f};
  const float4 bb = *reinterpret_cast<const float4*>(b1 + 4 * cl);

  for (int node = blockIdx.x * 4 + wv; node < N; node += nodeStride) {
    const int beg = rowptr[node], end = rowptr[node + 1];
    float a0 = 0.f, a1 = 0.f, a2 = 0.f, a3 = 0.f;
    if (q == 1) {   // self term (pre-reduction: any single quarter)
      ushort4 h = *reinterpret_cast<const ushort4*>(P + (long long)node * 64 + 4 * cl);
      a0 = bf2f(h.x); a1 = bf2f(h.y); a2 = bf2f(h.z); a3 = bf2f(h.w);
    } else if (q == 2) {  // bias (pre-reduction)
      a0 = bb.x; a1 = bb.y; a2 = bb.z; a3 = bb.w;
    }
    int j = beg + q;
    for (; j + 12 < end; j += 16) {   // 16 edges in flight per wave
      int rA = col[j], rB = col[j + 4], rC = col[j + 8], rD = col[j + 12];
      ushort4 hA = *reinterpret_cast<const ushort4*>(P + (long long)rA * 64 + 4 * cl);
      ushort4 hB = *reinterpret_cast<const ushort4*>(P + (long long)rB * 64 + 4 * cl);
      ushort4 hC = *reinterpret_cast<const ushort4*>(P + (long long)rC * 64 + 4 * cl);
      ushort4 hD = *reinterpret_cast<const ushort4*>(P + (long long)rD * 64 + 4 * cl);
      a0 += bf2f(hA.x); a1 += bf2f(hA.y); a2 += bf2f(hA.z); a3 += bf2f(hA.w);
      a0 += bf2f(hB.x); a1 += bf2f(hB.y); a2 += bf2f(hB.z); a3 += bf2f(hB.w);
      a0 += bf2f(hC.x); a1 += bf2f(hC.y); a2 += bf2f(hC.z); a3 += bf2f(hC.w);
      a0 += bf2f(hD.x); a1 += bf2f(hD.y); a2 += bf2f(hD.z); a3 += bf2f(hD.w);
    }
    for (; j < end; j += 4) {
      int rA = col[j];
      ushort4 hA = *reinterpret_cast<const ushort4*>(P + (long long)rA * 64 + 4 * cl);
      a0 += bf2f(hA.x); a1 += bf2f(hA.y); a2 += bf2f(hA.z); a3 += bf2f(hA.w);
    }
    // reduce across quarters (lanes cl, 16+cl, 32+cl, 48+cl)
    a0 += __shfl_xor(a0, 16); a0 += __shfl_xor(a0, 32);
    a1 += __shfl_xor(a1, 16); a1 += __shfl_xor(a1, 32);
    a2 += __shfl_xor(a2, 16); a2 += __shfl_xor(a2, 32);
    a3 += __shfl_xor(a3, 16); a3 += __shfl_xor(a3, 32);
    if (q == 0) {   // writer
      *reinterpret_cast<float4*>(A + (long long)node * 64 + 4 * cl) =
          make_float4(a0, a1, a2, a3);
    } else if (q == 1) {  // stats keeper (same totals post-reduction)
      float r0 = fmaxf(a0, 0.f), r1 = fmaxf(a1, 0.f);
      float r2 = fmaxf(a2, 0.f), r3 = fmaxf(a3, 0.f);
      s[0] += r0; s[1] += r1; s[2] += r2; s[3] += r3;
      sq[0] += r0 * r0; sq[1] += r1 * r1; sq[2] += r2 * r2; sq[3] += r3 * r3;
    }
  }

  __shared__ float st[4][16][8];   // [wave][cl][{s0..s3,q0..q3}]
  if (q == 1) {
    st[wv][cl][0] = s[0]; st[wv][cl][1] = s[1]; st[wv][cl][2] = s[2]; st[wv][cl][3] = s[3];
    st[wv][cl][4] = sq[0]; st[wv][cl][5] = sq[1]; st[wv][cl][6] = sq[2]; st[wv][cl][7] = sq[3];
  }
  __syncthreads();
  if (threadIdx.x < 128) {
    int c = threadIdx.x;          // 0..63 -> sum, 64..127 -> sumsq
    int colid = c & 63, part = c >> 6;
    int idx = (part ? 4 : 0) + (colid & 3);
    float v = st[0][colid >> 2][idx] + st[1][colid >> 2][idx]
            + st[2][colid >> 2][idx] + st[3][colid >> 2][idx];
    atomicAdd(&stats[c], v);
  }
}

// ---------------- fold BN into W2/b2 ----------------
__global__ void bn_fold(
    const float* __restrict__ stats, const float* __restrict__ g, const float* __restrict__ be,
    const float* __restrict__ W2, const float* __restrict__ b2,
    float* __restrict__ W2f, float* __restrict__ b2f, float invN)
{
  int j = threadIdx.x;
  __shared__ float sc[64], sh[64];
  float mu = stats[j] * invN;
  float var = stats[64 + j] * invN - mu * mu;
  float s = g[j] * rsqrtf(var + 1e-5f);
  sc[j] = s;
  sh[j] = be[j] - mu * s;
  __syncthreads();
  float acc = b2[j];
  for (int k = 0; k < 64; ++k) {
    float w = W2[k * 64 + j];
    W2f[k * 64 + j] = sc[k] * w;
    acc += sh[k] * w;
  }
  b2f[j] = acc;
}

// ---------------- global add pool over sorted batch ----------------
__global__ __launch_bounds__(256) void pool_sorted(
    const float* __restrict__ Hf, const int* __restrict__ batch,
    float* __restrict__ out, int N, int G)
{
  int g = blockIdx.x * 4 + (threadIdx.x >> 6);
  int c = threadIdx.x & 63;
  if (g >= G) return;
  int lo = 0, hi = N;
  while (lo < hi) { int mid = (lo + hi) >> 1; if (batch[mid] < g) lo = mid + 1; else hi = mid; }
  int beg = lo;
  hi = N;
  while (lo < hi) { int mid = (lo + hi) >> 1; if (batch[mid] < g + 1) lo = mid + 1; else hi = mid; }
  int end = lo;
  float acc = 0.f;
  for (int r = beg; r < end; ++r) acc += Hf[(long long)r * 64 + c];
  out[(long long)g * 64 + c] = acc;
}

extern "C" void kernel_launch(void* const* d_in, const int* in_sizes, int n_in,
                              void* d_out, int out_size, void* d_ws, size_t ws_size,
                              hipStream_t stream) {
  const float* x      = (const float*)d_in[0];
  const int*   ei     = (const int*)d_in[1];
  const int*   batch  = (const int*)d_in[2];
  const float* W1_0 = (const float*)d_in[3];
  const float* b1_0 = (const float*)d_in[4];
  const float* g_0  = (const float*)d_in[5];
  const float* be_0 = (const float*)d_in[6];
  const float* W2_0 = (const float*)d_in[7];
  const float* b2_0 = (const float*)d_in[8];
  const float* W1_1 = (const float*)d_in[9];
  const float* b1_1 = (const float*)d_in[10];
  const float* g_1  = (const float*)d_in[11];
  const float* be_1 = (const float*)d_in[12];
  const float* W2_1 = (const float*)d_in[13];
  const float* b2_1 = (const float*)d_in[14];

  const int N = in_sizes[0] / 128;
  const int E = in_sizes[1] / 2;
  const int G = (out_size - N * 64) / 64;
  const int* srcI = ei;
  const int* dstI = ei + E;

  float* outG = (float*)d_out;                       // [G,64]
  float* outH = (float*)d_out + (long long)G * 64;   // [N,64] fp32 (doubles as A buffer)

  const int NB = cdiv_ll(N, NPB);
  const int nblocksB = cdiv_ll(E, EB_CHUNK);

  // ---- workspace layout ----
  char* w = (char*)d_ws;
  size_t r2 = (size_t)E * 4;
  if ((size_t)N * 64 * 2 > r2) r2 = (size_t)N * 64 * 2;
  unsigned* ebuf        = (unsigned*)w;              // CSR-build only
  unsigned short* Pbuf  = (unsigned short*)w;        // bf16 P table (aliases ebuf)
  w += r2;
  int* col       = (int*)w; w += (size_t)E * 4;
  int* rowptr    = (int*)w; w += (size_t)(N + 1) * 4;
  int* blockHist = (int*)w; w += (size_t)NB * nblocksB * 4;
  int* bucketTotal = (int*)w; w += (size_t)NB * 4;
  int* bucketBase  = (int*)w; w += (size_t)(NB + 1) * 4;
  float* stats0 = (float*)w; w += 128 * 4;
  float* stats1 = (float*)w; w += 128 * 4;
  float* W2f0   = (float*)w; w += 64 * 64 * 4;
  float* b2f0   = (float*)w; w += 64 * 4;
  float* W2f1   = (float*)w; w += 64 * 64 * 4;
  float* b2f1   = (float*)w; w += 64 * 4;

  const int gemmGrid = cdiv_ll(N, 64);
  const int gatherGrid = 2048;                       // 8 blocks/CU -> full wave slots

  hipMemsetAsync(stats0, 0, 256 * sizeof(float), stream);

  // ---- CSR build ----
  part_hist<<<nblocksB, 256, 0, stream>>>(dstI, blockHist, E, NB, nblocksB);
  scan_bucket_blocks<<<NB, 256, 0, stream>>>(blockHist, bucketTotal, nblocksB);
  scan_buckets<<<1, 512, 0, stream>>>(bucketTotal, bucketBase, NB);
  part_scatter<<<nblocksB, 256, 0, stream>>>(srcI, dstI, blockHist, bucketBase, ebuf, E, NB, nblocksB);
  bucket_csr<<<NB, 256, 0, stream>>>(ebuf, bucketBase, rowptr, col, N, NB);

  // ---- layer 0 ----
  gemm64x64<128, false, false, false, false, true><<<gemmGrid, 256, 0, stream>>>(x, W1_0, nullptr, Pbuf, N);
  gin_gather_bf16<<<gatherGrid, 256, 0, stream>>>(rowptr, col, Pbuf, b1_0, outH, stats0, N, gatherGrid * 4);
  bn_fold<<<1, 64, 0, stream>>>(stats0, g_0, be_0, W2_0, b2_0, W2f0, b2f0, 1.0f / N);
  gemm_dual<<<gemmGrid, 256, 0, stream>>>(outH, W2f0, b2f0, W1_1, Pbuf, N);

  // ---- layer 1 ----
  gin_gather_bf16<<<gatherGrid, 256, 0, stream>>>(rowptr, col, Pbuf, b1_1, outH, stats1, N, gatherGrid * 4);
  bn_fold<<<1, 64, 0, stream>>>(stats1, g_1, be_1, W2_1, b2_1, W2f1, b2f1, 1.0f / N);
  gemm64x64<64, false, true, true, true, false><<<gemmGrid, 256, 0, stream>>>(outH, W2f1, b2f1, outH, N);

  // ---- global add pool ----
  pool_sorted<<<cdiv_ll(G, 4), 256, 0, stream>>>(outH, batch, outG, N, G);
}

// Round 7
// 408.159 us; speedup vs baseline: 14.2334x; 1.0781x over previous
//
#include <hip/hip_runtime.h>

static inline int cdiv_ll(long long a, long long b){ return (int)((a + b - 1) / b); }

#define EB_CHUNK 8192   // edges per partition block
#define NPB 256         // nodes per bucket (pow2: bucket = dst >> 8)
#define MAXNB 512       // max buckets supported in LDS
#define CSR_LDS 10240   // LDS-staged edges per bucket (avg 8192; Poisson tail safe)

typedef short bf16x8 __attribute__((ext_vector_type(8)));
typedef float f32x4 __attribute__((ext_vector_type(4)));

__device__ __forceinline__ float bf2f(unsigned short h) {
  unsigned u = (unsigned)h << 16;
  return __uint_as_float(u);
}
__device__ __forceinline__ unsigned short f2bf(float f) {
  unsigned u = __float_as_uint(f);
  u += 0x7FFF + ((u >> 16) & 1);   // round-to-nearest-even
  return (unsigned short)(u >> 16);
}

// XOR swizzle: spread row-strided 16B reads across banks (guide G4)
#define SWZ(row, byteoff) ((byteoff) ^ (((row) & 7) << 4))

// ---- stage X[M,K] fp32 (optional relu) -> LDS bf16 [64][K], swizzled ----
template<int K, bool RELU>
__device__ __forceinline__ void stage_x_bf16(
    char* XlB, const float* __restrict__ X, long long rb, int M)
{
  for (int f = threadIdx.x; f < 16 * K; f += 256) {   // 64 rows * K/4 col-chunks
    int r = f / (K / 4), c4 = (f % (K / 4)) * 4;
    float4 v = make_float4(0.f, 0.f, 0.f, 0.f);
    if (rb + r < M) {
      v = *reinterpret_cast<const float4*>(X + (rb + r) * K + c4);
      if (RELU) {
        v.x = fmaxf(v.x, 0.f); v.y = fmaxf(v.y, 0.f);
        v.z = fmaxf(v.z, 0.f); v.w = fmaxf(v.w, 0.f);
      }
    }
    ushort4 h; h.x = f2bf(v.x); h.y = f2bf(v.y); h.z = f2bf(v.z); h.w = f2bf(v.w);
    *reinterpret_cast<ushort4*>(XlB + r * (2 * K) + SWZ(r, c4 * 2)) = h;
  }
}

// ---- stage W[K,64] fp32 -> LDS bf16 W^T [64][K], swizzled ----
template<int K>
__device__ __forceinline__ void stage_wt_bf16(char* WTB, const float* __restrict__ W)
{
  for (int t = threadIdx.x; t < K * 32; t += 256) {   // K/2 k-pairs * 64 cols
    int c = t & 63, kp = t >> 6;
    float w0 = W[(2 * kp) * 64 + c];
    float w1 = W[(2 * kp + 1) * 64 + c];
    ushort2 hh; hh.x = f2bf(w0); hh.y = f2bf(w1);
    *reinterpret_cast<ushort2*>(WTB + c * (2 * K) + SWZ(c, 4 * kp)) = hh;
  }
}

// ---- MFMA chain: acc[ct] += Xl[16w..16w+15][:] @ WT[ct*16..][:]  (K-loop) ----
template<int K>
__device__ __forceinline__ void mfma_chain(
    f32x4* acc, const char* XlB, const char* WTB, int wv, int lr, int lg)
{
  const int rowb = 16 * wv + lr;
  #pragma unroll
  for (int kc = 0; kc < K / 32; ++kc) {
    const int kByte = kc * 64 + lg * 16;
    bf16x8 a = *reinterpret_cast<const bf16x8*>(XlB + rowb * (2 * K) + SWZ(rowb, kByte));
    #pragma unroll
    for (int ct = 0; ct < 4; ++ct) {
      int c = ct * 16 + lr;
      bf16x8 b = *reinterpret_cast<const bf16x8*>(WTB + c * (2 * K) + SWZ(c, kByte));
      acc[ct] = __builtin_amdgcn_mfma_f32_16x16x32_bf16(a, b, acc[ct], 0, 0, 0);
    }
  }
}

// ---------------- MFMA GEMM: Y[M,64] = act(op(X[M,K]) @ W[K,64] (+b)) ----------------
template<int K, bool IN_RELU, bool RELU_OUT, bool BIAS, bool OUT_BF16>
__global__ __launch_bounds__(256) void mfma_gemm(
    const float* __restrict__ X, const float* __restrict__ W,
    const float* __restrict__ bias, void* __restrict__ Yv, int M)
{
  __shared__ __align__(16) char XlB[64 * 2 * K];
  __shared__ __align__(16) char WTB[64 * 2 * K];
  const long long rb = (long long)blockIdx.x * 64;
  stage_x_bf16<K, IN_RELU>(XlB, X, rb, M);
  stage_wt_bf16<K>(WTB, W);
  __syncthreads();

  const int lane = threadIdx.x & 63, wv = threadIdx.x >> 6;
  const int lr = lane & 15, lg = lane >> 4;
  f32x4 acc[4] = {};
  mfma_chain<K>(acc, XlB, WTB, wv, lr, lg);

  #pragma unroll
  for (int ct = 0; ct < 4; ++ct) {
    const int c = ct * 16 + lr;
    const float bv = BIAS ? bias[c] : 0.0f;
    #pragma unroll
    for (int j = 0; j < 4; ++j) {
      long long row = rb + 16 * wv + lg * 4 + j;
      if (row < M) {
        float v = acc[ct][j] + bv;
        if (RELU_OUT) v = fmaxf(v, 0.f);
        if (OUT_BF16) ((unsigned short*)Yv)[row * 64 + c] = f2bf(v);
        else          ((float*)Yv)[row * 64 + c] = v;
      }
    }
  }
}

// ---- fused MFMA pair: P = (relu(relu(A)@Wa + ba)) @ Wb   (A fp32 -> P bf16) ----
__global__ __launch_bounds__(256) void mfma_dual(
    const float* __restrict__ A, const float* __restrict__ Wa,
    const float* __restrict__ ba, const float* __restrict__ Wb,
    unsigned short* __restrict__ P, int M)
{
  __shared__ __align__(16) char XlB[64 * 128];
  __shared__ __align__(16) char WTaB[64 * 128];
  __shared__ __align__(16) char WTbB[64 * 128];
  __shared__ __align__(16) char Xl2B[64 * 128];
  const long long rb = (long long)blockIdx.x * 64;
  stage_x_bf16<64, true>(XlB, A, rb, M);
  stage_wt_bf16<64>(WTaB, Wa);
  stage_wt_bf16<64>(WTbB, Wb);
  __syncthreads();

  const int lane = threadIdx.x & 63, wv = threadIdx.x >> 6;
  const int lr = lane & 15, lg = lane >> 4;
  f32x4 acc[4] = {};
  mfma_chain<64>(acc, XlB, WTaB, wv, lr, lg);

  // h = relu(acc + ba) -> restage as bf16 A-operand (swizzled)
  #pragma unroll
  for (int ct = 0; ct < 4; ++ct) {
    const int c = ct * 16 + lr;
    const float bv = ba[c];
    #pragma unroll
    for (int j = 0; j < 4; ++j) {
      int rloc = 16 * wv + lg * 4 + j;
      float v = fmaxf(acc[ct][j] + bv, 0.f);
      *reinterpret_cast<unsigned short*>(Xl2B + rloc * 128 + SWZ(rloc, c * 2)) = f2bf(v);
    }
  }
  __syncthreads();

  f32x4 ac2[4] = {};
  mfma_chain<64>(ac2, Xl2B, WTbB, wv, lr, lg);

  #pragma unroll
  for (int ct = 0; ct < 4; ++ct) {
    const int c = ct * 16 + lr;
    #pragma unroll
    for (int j = 0; j < 4; ++j) {
      long long row = rb + 16 * wv + lg * 4 + j;
      if (row < M) P[row * 64 + c] = f2bf(ac2[ct][j]);
    }
  }
}

// ---------------- partition pass 1: per-block bucket histogram ----------------
__global__ __launch_bounds__(256) void part_hist(
    const int* __restrict__ dst, int* __restrict__ blockHist,
    int E, int NB, int nblocksB)
{
  __shared__ int hist[MAXNB];
  for (int i = threadIdx.x; i < NB; i += 256) hist[i] = 0;
  __syncthreads();
  int base = blockIdx.x * EB_CHUNK;
  int end = min(base + EB_CHUNK, E);
  for (int e = base + threadIdx.x; e < end; e += 256)
    atomicAdd(&hist[dst[e] >> 8], 1);
  __syncthreads();
  for (int i = threadIdx.x; i < NB; i += 256)
    blockHist[(long long)i * nblocksB + blockIdx.x] = hist[i];
}

// ---------------- scan blockHist within each bucket ----------------
__global__ __launch_bounds__(256) void scan_bucket_blocks(
    int* __restrict__ blockHist, int* __restrict__ bucketTotal, int nblocksB)
{
  int* row = blockHist + (long long)blockIdx.x * nblocksB;
  __shared__ int tsum[256];
  int v[4]; int local = 0;
  int i0 = threadIdx.x * 4;
  #pragma unroll
  for (int k = 0; k < 4; ++k) { int g = i0 + k; v[k] = (g < nblocksB) ? row[g] : 0; local += v[k]; }
  tsum[threadIdx.x] = local;
  __syncthreads();
  for (int off = 1; off < 256; off <<= 1) {
    int y = (threadIdx.x >= off) ? tsum[threadIdx.x - off] : 0;
    __syncthreads();
    tsum[threadIdx.x] += y;
    __syncthreads();
  }
  int pref = tsum[threadIdx.x] - local;
  #pragma unroll
  for (int k = 0; k < 4; ++k) { int g = i0 + k; if (g < nblocksB) { row[g] = pref; pref += v[k]; } }
  if (threadIdx.x == 255) bucketTotal[blockIdx.x] = tsum[255];
}

// ---------------- exclusive scan of bucket totals ----------------
__global__ __launch_bounds__(512) void scan_buckets(
    const int* __restrict__ bucketTotal, int* __restrict__ bucketBase, int NB)
{
  __shared__ int tsum[512];
  int t = threadIdx.x;
  int v = (t < NB) ? bucketTotal[t] : 0;
  tsum[t] = v;
  __syncthreads();
  for (int off = 1; off < 512; off <<= 1) {
    int y = (t >= off) ? tsum[t - off] : 0;
    __syncthreads();
    tsum[t] += y;
    __syncthreads();
  }
  if (t < NB) bucketBase[t] = tsum[t] - v;
  if (t == NB - 1) bucketBase[NB] = tsum[t];
}

// ---------------- partition pass 2: scatter packed (src | localDst<<24) ----------------
__global__ __launch_bounds__(256) void part_scatter(
    const int* __restrict__ src, const int* __restrict__ dst,
    const int* __restrict__ blockHist, const int* __restrict__ bucketBase,
    unsigned* __restrict__ ebuf, int E, int NB, int nblocksB)
{
  __shared__ int cursor[MAXNB];
  for (int i = threadIdx.x; i < NB; i += 256)
    cursor[i] = bucketBase[i] + blockHist[(long long)i * nblocksB + blockIdx.x];
  __syncthreads();
  int base = blockIdx.x * EB_CHUNK;
  int end = min(base + EB_CHUNK, E);
  for (int e = base + threadIdx.x; e < end; e += 256) {
    int s = src[e], d = dst[e];
    int p = atomicAdd(&cursor[d >> 8], 1);
    ebuf[p] = (unsigned)s | ((unsigned)(d & (NPB - 1)) << 24);
  }
}

// ---------------- per-bucket counting sort -> rowptr + col (LDS-staged edges) --------
__global__ __launch_bounds__(256) void bucket_csr(
    const unsigned* __restrict__ ebuf, const int* __restrict__ bucketBase,
    int* __restrict__ rowptr, int* __restrict__ col, int N, int NB)
{
  int b = blockIdx.x;
  int eb = bucketBase[b], ee = bucketBase[b + 1];
  int cnt = ee - eb;
  int nodeBase = b * NPB;
  __shared__ unsigned ebl[CSR_LDS];
  __shared__ int hist[NPB];
  __shared__ int tsum[NPB];
  __shared__ int cur[NPB];
  const bool fit = (cnt <= CSR_LDS);
  hist[threadIdx.x] = 0;
  if (fit) for (int i = threadIdx.x; i < cnt; i += 256) ebl[i] = ebuf[eb + i];
  __syncthreads();
  for (int i = threadIdx.x; i < cnt; i += 256)
    atomicAdd(&hist[(fit ? ebl[i] : ebuf[eb + i]) >> 24], 1);
  __syncthreads();
  int local = hist[threadIdx.x];
  tsum[threadIdx.x] = local;
  __syncthreads();
  for (int off = 1; off < 256; off <<= 1) {
    int y = (threadIdx.x >= off) ? tsum[threadIdx.x - off] : 0;
    __syncthreads();
    tsum[threadIdx.x] += y;
    __syncthreads();
  }
  int pref = tsum[threadIdx.x] - local;
  int node = nodeBase + threadIdx.x;
  if (node < N) rowptr[node] = eb + pref;
  if (b == NB - 1 && threadIdx.x == 0) rowptr[N] = ee;
  cur[threadIdx.x] = pref;
  __syncthreads();
  for (int i = threadIdx.x; i < cnt; i += 256) {
    unsigned w = fit ? ebl[i] : ebuf[eb + i];
    int l = (int)(w >> 24);
    int p = eb + atomicAdd(&cur[l], 1);
    col[p] = (int)(w & 0xFFFFFFu);
  }
}

// ---- GIN aggregate: quarter-wave rows (ushort4/lane, 16 lanes/row, 4 edges in flight) ----
__global__ __launch_bounds__(256) void gin_gather_bf16(
    const int* __restrict__ rowptr, const int* __restrict__ col,
    const unsigned short* __restrict__ P, const float* __restrict__ b1,
    float* __restrict__ A, float* __restrict__ stats, int N, int nodeStride)
{
  const int lane = threadIdx.x & 63;
  const int wv = threadIdx.x >> 6;
  const int q = lane >> 4;          // quarter 0..3 (edge interleave)
  const int cl = lane & 15;         // col group: cols 4cl..4cl+3
  float s[4] = {0.f, 0.f, 0.f, 0.f};
  float sq[4] = {0.f, 0.f, 0.f, 0.f};
  const float4 bb = *reinterpret_cast<const float4*>(b1 + 4 * cl);

  for (int node = blockIdx.x * 4 + wv; node < N; node += nodeStride) {
    const int beg = rowptr[node], end = rowptr[node + 1];
    float a0 = 0.f, a1 = 0.f, a2 = 0.f, a3 = 0.f;
    if (q == 1) {
      ushort4 h = *reinterpret_cast<const ushort4*>(P + (long long)node * 64 + 4 * cl);
      a0 = bf2f(h.x); a1 = bf2f(h.y); a2 = bf2f(h.z); a3 = bf2f(h.w);
    } else if (q == 2) {
      a0 = bb.x; a1 = bb.y; a2 = bb.z; a3 = bb.w;
    }
    int j = beg + q;
    for (; j + 12 < end; j += 16) {
      int rA = col[j], rB = col[j + 4], rC = col[j + 8], rD = col[j + 12];
      ushort4 hA = *reinterpret_cast<const ushort4*>(P + (long long)rA * 64 + 4 * cl);
      ushort4 hB = *reinterpret_cast<const ushort4*>(P + (long long)rB * 64 + 4 * cl);
      ushort4 hC = *reinterpret_cast<const ushort4*>(P + (long long)rC * 64 + 4 * cl);
      ushort4 hD = *reinterpret_cast<const ushort4*>(P + (long long)rD * 64 + 4 * cl);
      a0 += bf2f(hA.x); a1 += bf2f(hA.y); a2 += bf2f(hA.z); a3 += bf2f(hA.w);
      a0 += bf2f(hB.x); a1 += bf2f(hB.y); a2 += bf2f(hB.z); a3 += bf2f(hB.w);
      a0 += bf2f(hC.x); a1 += bf2f(hC.y); a2 += bf2f(hC.z); a3 += bf2f(hC.w);
      a0 += bf2f(hD.x); a1 += bf2f(hD.y); a2 += bf2f(hD.z); a3 += bf2f(hD.w);
    }
    for (; j < end; j += 4) {
      int rA = col[j];
      ushort4 hA = *reinterpret_cast<const ushort4*>(P + (long long)rA * 64 + 4 * cl);
      a0 += bf2f(hA.x); a1 += bf2f(hA.y); a2 += bf2f(hA.z); a3 += bf2f(hA.w);
    }
    a0 += __shfl_xor(a0, 16); a0 += __shfl_xor(a0, 32);
    a1 += __shfl_xor(a1, 16); a1 += __shfl_xor(a1, 32);
    a2 += __shfl_xor(a2, 16); a2 += __shfl_xor(a2, 32);
    a3 += __shfl_xor(a3, 16); a3 += __shfl_xor(a3, 32);
    if (q == 0) {
      *reinterpret_cast<float4*>(A + (long long)node * 64 + 4 * cl) =
          make_float4(a0, a1, a2, a3);
    } else if (q == 1) {
      float r0 = fmaxf(a0, 0.f), r1 = fmaxf(a1, 0.f);
      float r2 = fmaxf(a2, 0.f), r3 = fmaxf(a3, 0.f);
      s[0] += r0; s[1] += r1; s[2] += r2; s[3] += r3;
      sq[0] += r0 * r0; sq[1] += r1 * r1; sq[2] += r2 * r2; sq[3] += r3 * r3;
    }
  }

  __shared__ float st[4][16][8];
  if (q == 1) {
    st[wv][cl][0] = s[0]; st[wv][cl][1] = s[1]; st[wv][cl][2] = s[2]; st[wv][cl][3] = s[3];
    st[wv][cl][4] = sq[0]; st[wv][cl][5] = sq[1]; st[wv][cl][6] = sq[2]; st[wv][cl][7] = sq[3];
  }
  __syncthreads();
  if (threadIdx.x < 128) {
    int c = threadIdx.x;
    int colid = c & 63, part = c >> 6;
    int idx = (part ? 4 : 0) + (colid & 3);
    float v = st[0][colid >> 2][idx] + st[1][colid >> 2][idx]
            + st[2][colid >> 2][idx] + st[3][colid >> 2][idx];
    atomicAdd(&stats[c], v);
  }
}

// ---------------- fold BN into W2/b2 ----------------
__global__ void bn_fold(
    const float* __restrict__ stats, const float* __restrict__ g, const float* __restrict__ be,
    const float* __restrict__ W2, const float* __restrict__ b2,
    float* __restrict__ W2f, float* __restrict__ b2f, float invN)
{
  int j = threadIdx.x;
  __shared__ float sc[64], sh[64];
  float mu = stats[j] * invN;
  float var = stats[64 + j] * invN - mu * mu;
  float s = g[j] * rsqrtf(var + 1e-5f);
  sc[j] = s;
  sh[j] = be[j] - mu * s;
  __syncthreads();
  float acc = b2[j];
  for (int k = 0; k < 64; ++k) {
    float w = W2[k * 64 + j];
    W2f[k * 64 + j] = sc[k] * w;
    acc += sh[k] * w;
  }
  b2f[j] = acc;
}

// ---------------- global add pool over sorted batch ----------------
__global__ __launch_bounds__(256) void pool_sorted(
    const float* __restrict__ Hf, const int* __restrict__ batch,
    float* __restrict__ out, int N, int G)
{
  int g = blockIdx.x * 4 + (threadIdx.x >> 6);
  int c = threadIdx.x & 63;
  if (g >= G) return;
  int lo = 0, hi = N;
  while (lo < hi) { int mid = (lo + hi) >> 1; if (batch[mid] < g) lo = mid + 1; else hi = mid; }
  int beg = lo;
  hi = N;
  while (lo < hi) { int mid = (lo + hi) >> 1; if (batch[mid] < g + 1) lo = mid + 1; else hi = mid; }
  int end = lo;
  float acc = 0.f;
  for (int r = beg; r < end; ++r) acc += Hf[(long long)r * 64 + c];
  out[(long long)g * 64 + c] = acc;
}

extern "C" void kernel_launch(void* const* d_in, const int* in_sizes, int n_in,
                              void* d_out, int out_size, void* d_ws, size_t ws_size,
                              hipStream_t stream) {
  const float* x      = (const float*)d_in[0];
  const int*   ei     = (const int*)d_in[1];
  const int*   batch  = (const int*)d_in[2];
  const float* W1_0 = (const float*)d_in[3];
  const float* b1_0 = (const float*)d_in[4];
  const float* g_0  = (const float*)d_in[5];
  const float* be_0 = (const float*)d_in[6];
  const float* W2_0 = (const float*)d_in[7];
  const float* b2_0 = (const float*)d_in[8];
  const float* W1_1 = (const float*)d_in[9];
  const float* b1_1 = (const float*)d_in[10];
  const float* g_1  = (const float*)d_in[11];
  const float* be_1 = (const float*)d_in[12];
  const float* W2_1 = (const float*)d_in[13];
  const float* b2_1 = (const float*)d_in[14];

  const int N = in_sizes[0] / 128;
  const int E = in_sizes[1] / 2;
  const int G = (out_size - N * 64) / 64;
  const int* srcI = ei;
  const int* dstI = ei + E;

  float* outG = (float*)d_out;                       // [G,64]
  float* outH = (float*)d_out + (long long)G * 64;   // [N,64] fp32 (doubles as A buffer)

  const int NB = cdiv_ll(N, NPB);
  const int nblocksB = cdiv_ll(E, EB_CHUNK);

  // ---- workspace layout ----
  char* w = (char*)d_ws;
  size_t r2 = (size_t)E * 4;
  if ((size_t)N * 64 * 2 > r2) r2 = (size_t)N * 64 * 2;
  unsigned* ebuf        = (unsigned*)w;              // CSR-build only
  unsigned short* Pbuf  = (unsigned short*)w;        // bf16 P table (aliases ebuf)
  w += r2;
  int* col       = (int*)w; w += (size_t)E * 4;
  int* rowptr    = (int*)w; w += (size_t)(N + 1) * 4;
  int* blockHist = (int*)w; w += (size_t)NB * nblocksB * 4;
  int* bucketTotal = (int*)w; w += (size_t)NB * 4;
  int* bucketBase  = (int*)w; w += (size_t)(NB + 1) * 4;
  float* stats0 = (float*)w; w += 128 * 4;
  float* stats1 = (float*)w; w += 128 * 4;
  float* W2f0   = (float*)w; w += 64 * 64 * 4;
  float* b2f0   = (float*)w; w += 64 * 4;
  float* W2f1   = (float*)w; w += 64 * 64 * 4;
  float* b2f1   = (float*)w; w += 64 * 4;

  const int gemmGrid = cdiv_ll(N, 64);
  const int gatherGrid = 2048;

  hipMemsetAsync(stats0, 0, 256 * sizeof(float), stream);

  // ---- CSR build ----
  part_hist<<<nblocksB, 256, 0, stream>>>(dstI, blockHist, E, NB, nblocksB);
  scan_bucket_blocks<<<NB, 256, 0, stream>>>(blockHist, bucketTotal, nblocksB);
  scan_buckets<<<1, 512, 0, stream>>>(bucketTotal, bucketBase, NB);
  part_scatter<<<nblocksB, 256, 0, stream>>>(srcI, dstI, blockHist, bucketBase, ebuf, E, NB, nblocksB);
  bucket_csr<<<NB, 256, 0, stream>>>(ebuf, bucketBase, rowptr, col, N, NB);

  // ---- layer 0 ----
  // P0 = x @ W1_0 -> bf16 (MFMA; ebuf dead)
  mfma_gemm<128, false, false, false, true><<<gemmGrid, 256, 0, stream>>>(x, W1_0, nullptr, Pbuf, N);
  gin_gather_bf16<<<gatherGrid, 256, 0, stream>>>(rowptr, col, Pbuf, b1_0, outH, stats0, N, gatherGrid * 4);
  bn_fold<<<1, 64, 0, stream>>>(stats0, g_0, be_0, W2_0, b2_0, W2f0, b2f0, 1.0f / N);
  // h1 = relu(relu(A0)@W2f0+b2f0); P1 = h1@W1_1 -> bf16 (fused MFMA pair)
  mfma_dual<<<gemmGrid, 256, 0, stream>>>(outH, W2f0, b2f0, W1_1, Pbuf, N);

  // ---- layer 1 ----
  gin_gather_bf16<<<gatherGrid, 256, 0, stream>>>(rowptr, col, Pbuf, b1_1, outH, stats1, N, gatherGrid * 4);
  bn_fold<<<1, 64, 0, stream>>>(stats1, g_1, be_1, W2_1, b2_1, W2f1, b2f1, 1.0f / N);
  // h2 = relu(relu(A1)@W2f1+b2f1) -> fp32 in-place in outH (MFMA)
  mfma_gemm<64, true, true, true, false><<<gemmGrid, 256, 0, stream>>>(outH, W2f1, b2f1, outH, N);

  // ---- global add pool ----
  pool_sorted<<<cdiv_ll(G, 4), 256, 0, stream>>>(outH, batch, outG, N, G);
}